// Round 5
// baseline (1751.664 us; speedup 1.0000x reference)
//
#include <hip/hip_runtime.h>
#include <stdint.h>

#define TOK    8192   // B*L
#define LDIM   4096
#define DDIM   2048
#define NBH    16     // B*H
#define DK     256
#define NCHUNK 64
#define DVS    16     // v-slice width per scan block

typedef __attribute__((ext_vector_type(8))) short bf16x8;   // 8 bf16 (4 VGPRs)
typedef __attribute__((ext_vector_type(4))) float f32x4;

#define MFMA(a,b,c) __builtin_amdgcn_mfma_f32_16x16x32_bf16((a),(b),(c),0,0,0)

__device__ __forceinline__ unsigned short f2bf(float f){
  union { float f; uint32_t u; } v; v.f = f;
  uint32_t r = v.u + 0x7FFFu + ((v.u >> 16) & 1u);   // RNE
  return (unsigned short)(r >> 16);
}
__device__ __forceinline__ float bf2f(unsigned short u){
  union { uint32_t u; float f; } v; v.u = ((uint32_t)u) << 16;
  return v.f;
}

typedef __attribute__((address_space(1))) unsigned int as1_u32;
typedef __attribute__((address_space(3))) unsigned int as3_u32;
__device__ __forceinline__ void gload16(const void* g, void* l){
  __builtin_amdgcn_global_load_lds((const as1_u32*)g, (as3_u32*)l, 16, 0, 0);
}

// ---------------- guard (ws too small): clean fail, non-empty graph ----------------
__global__ void k_guard(float* o){ if (threadIdx.x == 0) o[0] = 0.f; }

// ---------------- f32 -> bf16 cast ----------------
__global__ __launch_bounds__(256) void k_f2bf(const float* __restrict__ s,
                                              unsigned short* __restrict__ d, int n)
{
  int i = (blockIdx.x*256 + threadIdx.x)*4;
  if (i >= n) return;
  float4 v = *(const float4*)(s + i);
  ushort4 o; o.x=f2bf(v.x); o.y=f2bf(v.y); o.z=f2bf(v.z); o.w=f2bf(v.w);
  *(ushort4*)(d + i) = o;
}

// ---------------- beta = sigmoid(hs @ Wb^T), [bh][l] ----------------
__global__ __launch_bounds__(256) void k_beta(const float* __restrict__ hs,
                                              const float* __restrict__ Wb,
                                              float* __restrict__ beta)
{
  const long t = blockIdx.x;          // token
  const int tid = threadIdx.x;
  float acc[8] = {0,0,0,0,0,0,0,0};
  const float* xr = hs + t*DDIM;
  for (int i = tid; i < DDIM; i += 256){
    float x = xr[i];
    #pragma unroll
    for (int h=0; h<8; h++) acc[h] += x * Wb[h*DDIM + i];
  }
  __shared__ float red[8][4];
  const int w = tid >> 6, lane = tid & 63;
  #pragma unroll
  for (int h=0; h<8; h++){
    float s = acc[h];
    #pragma unroll
    for (int off=32; off; off>>=1) s += __shfl_down(s, off, 64);
    if (lane == 0) red[h][w] = s;
  }
  __syncthreads();
  if (tid < 8){
    float s = red[tid][0]+red[tid][1]+red[tid][2]+red[tid][3];
    float bv = 1.f/(1.f + __expf(-s));
    int b = (int)(t >> 12), l = (int)(t & 4095);
    beta[((long)(b*8 + tid))*LDIM + l] = bv;
  }
}

// ---------------- GEMM: C[M,N] = A[M,K] * B[N,K]^T, bf16 in, bf16 or f32 out ----------------
template <bool F32OUT>
__global__ __launch_bounds__(256,2) void k_gemm_bt(
    const unsigned short* __restrict__ A, const unsigned short* __restrict__ Bw,
    void* __restrict__ Cv, int M, int N, int K)
{
  __shared__ unsigned short As[128*32];
  __shared__ unsigned short Bs[128*32];
  const int tid = threadIdx.x;
  const int w = tid >> 6, l = tid & 63;
  const int lo = l & 15, quad = l >> 4;
  const int wm = w >> 1, wn = w & 1;
  // T1: XCD-aware bijective block swizzle (nwg % 8 == 0 for all our launches)
  const int gx = gridDim.x;
  int id = blockIdx.y * gx + blockIdx.x;
  const int nwg = gx * gridDim.y;
  if ((nwg & 7) == 0){
    const int q8 = nwg >> 3;
    id = (id & 7) * q8 + (id >> 3);
  }
  const int bx = id % gx, by = id / gx;
  const long tm = (long)by * 128, tn = (long)bx * 128;
  const int slot0 = (w*2+0)*64 + l;        // LDS dest = wave-uniform base + lane*16B
  const int slot1 = (w*2+1)*64 + l;
  const int r0 = slot0 >> 2, c0 = (slot0 & 3) * 8;
  const int r1 = slot1 >> 2, c1 = (slot1 & 3) * 8;
  const unsigned short* pA0 = A  + (tm + r0)*(long)K + c0;
  const unsigned short* pA1 = A  + (tm + r1)*(long)K + c1;
  const unsigned short* pB0 = Bw + (tn + r0)*(long)K + c0;
  const unsigned short* pB1 = Bw + (tn + r1)*(long)K + c1;
  unsigned short* lA0 = &As[slot0*8]; unsigned short* lA1 = &As[slot1*8];
  unsigned short* lB0 = &Bs[slot0*8]; unsigned short* lB1 = &Bs[slot1*8];
  f32x4 acc[4][4] = {};
  for (int k0 = 0; k0 < K; k0 += 32){
    __syncthreads();
    gload16(pA0 + k0, lA0);
    gload16(pA1 + k0, lA1);
    gload16(pB0 + k0, lB0);
    gload16(pB1 + k0, lB1);
    __syncthreads();
    bf16x8 af[4], bg[4];
    #pragma unroll
    for (int i=0;i<4;i++){
      af[i] = *(const bf16x8*)&As[(wm*64 + i*16 + lo)*32 + quad*8];
      bg[i] = *(const bf16x8*)&Bs[(wn*64 + i*16 + lo)*32 + quad*8];
    }
    #pragma unroll
    for (int mt=0; mt<4; mt++)
      #pragma unroll
      for (int nt=0; nt<4; nt++)
        acc[mt][nt] = MFMA(af[mt], bg[nt], acc[mt][nt]);
  }
  #pragma unroll
  for (int mt=0; mt<4; mt++)
    #pragma unroll
    for (int nt=0; nt<4; nt++)
      #pragma unroll
      for (int r=0; r<4; r++){
        long m = tm + wm*64 + mt*16 + quad*4 + r;
        long n = tn + wn*64 + nt*16 + lo;
        if (F32OUT) ((float*)Cv)[m*N + n] = acc[mt][nt][r];
        else ((unsigned short*)Cv)[m*N + n] = f2bf(acc[mt][nt][r]);
      }
}

// ---------------- causal conv(K=4)+silu (+l2norm q/k, *beta for v), head layout out ----------------
// mode: 0=q (l2norm + dk^-0.5), 1=k (l2norm), 2=v (silu * beta)
__global__ __launch_bounds__(256) void k_conv(
  const unsigned short* __restrict__ X, const float* __restrict__ Wc,
  const float* __restrict__ beta,
  unsigned short* __restrict__ O, int mode)
{
  const int lt = blockIdx.x, bh = blockIdx.y;
  const int b = bh >> 3, h = bh & 7;
  const int d = threadIdx.x;                 // 0..255 within head
  const int ch = h*256 + d;
  const int l0 = lt*64;
  const unsigned short* xp = X + (long)b*LDIM*DDIM + ch;
  const float4 wv = *(const float4*)(Wc + ch*4);
  float x0=0.f, x1=0.f, x2=0.f;
  if (l0 >= 3){
    x0 = bf2f(xp[(long)(l0-3)*DDIM]);
    x1 = bf2f(xp[(long)(l0-2)*DDIM]);
    x2 = bf2f(xp[(long)(l0-1)*DDIM]);
  }
  float y[64];
  #pragma unroll
  for (int i=0;i<64;i++){
    float x3 = bf2f(xp[(long)(l0+i)*DDIM]);
    float s = x0*wv.x + x1*wv.y + x2*wv.z + x3*wv.w;
    y[i] = s / (1.f + __expf(-s));
    x0 = x1; x1 = x2; x2 = x3;
  }
  unsigned short* op = O + (long)bh*LDIM*DK + d;
  if (mode == 2){
    const float* bet = beta + (long)bh*LDIM + l0;
    #pragma unroll
    for (int i=0;i<64;i++) op[(long)(l0+i)*DK] = f2bf(y[i]*bet[i]);
    return;
  }
  __shared__ float red[64*4];
  __shared__ float scl[64];
  const int wv_i = threadIdx.x >> 6, lane = threadIdx.x & 63;
  #pragma unroll
  for (int i=0;i<64;i++){
    float ss = y[i]*y[i];
    #pragma unroll
    for (int off=32; off; off>>=1) ss += __shfl_down(ss, off, 64);
    if (lane == 0) red[i*4 + wv_i] = ss;
  }
  __syncthreads();
  if (threadIdx.x < 64){
    int i = threadIdx.x;
    float s = red[i*4]+red[i*4+1]+red[i*4+2]+red[i*4+3];
    scl[i] = rsqrtf(s + 1e-6f) * (mode==0 ? 0.0625f : 1.f);   // dk^-0.5 folded into q
  }
  __syncthreads();
  #pragma unroll
  for (int i=0;i<64;i++) op[(long)(l0+i)*DK] = f2bf(y[i]*scl[i]);
}

// ---------------- transpose k: CHUNK-TILED kT[bh][c][d][64] (rows 128B) ----------------
__global__ __launch_bounds__(256) void k_transpose(
  const unsigned short* __restrict__ kH, unsigned short* __restrict__ kT)
{
  const int lt = blockIdx.x, dt = blockIdx.y, bh = blockIdx.z;
  __shared__ unsigned short tk[64][72];   // 144B rows, 16B aligned
  const int tid = threadIdx.x;
  const int rl = tid >> 2, c0 = (tid & 3) * 16;
  const long base = ((long)bh*LDIM + lt*64 + rl)*DK + dt*64 + c0;
  *(bf16x8*)&tk[rl][c0]   = *(const bf16x8*)(kH + base);
  *(bf16x8*)&tk[rl][c0+8] = *(const bf16x8*)(kH + base + 8);
  __syncthreads();
  const int rd = tid >> 2, lc0 = (tid & 3) * 16;
  bf16x8 ok0, ok1;
  #pragma unroll
  for (int j=0;j<16;j++){
    unsigned short kraw = tk[lc0+j][rd];
    if (j < 8) ok0[j] = (short)kraw; else ok1[j-8] = (short)kraw;
  }
  const long ob = (((long)bh*NCHUNK + lt)*DK + dt*64 + rd)*64 + lc0;
  *(bf16x8*)(kT + ob) = ok0; *(bf16x8*)(kT + ob + 8) = ok1;
}

// ---------------- pass A: per (bh,chunk) attn, T=(I+M)^-1 (Neumann product), W=T*Kb, U=T*Vb ----------------
__global__ __launch_bounds__(256) void k_passA(
  const unsigned short* __restrict__ qH, const unsigned short* __restrict__ kH,
  const unsigned short* vbH,            // v*beta [bh][l][dk] (may alias Wout in fallback)
  const unsigned short* __restrict__ kT,
  const float* __restrict__ beta,
  unsigned short* Wout,
  unsigned short* __restrict__ Uout,
  unsigned short* __restrict__ Aout)
{
  const int c = blockIdx.x, bh = blockIdx.y;
  __shared__ unsigned short Nn[64*72];
  __shared__ unsigned short NT[64*72];
  __shared__ unsigned short Pb[64*72];
  __shared__ unsigned short vT[256*72];   // vb^T [d][s], stride 72 (63KiB total)
  const int tid = threadIdx.x;
  const int w = tid >> 6, l = tid & 63, lo = l & 15, quad = l >> 4;
  const long tokBase = (long)bh*LDIM + c*64;
  const unsigned short* qrow = qH + tokBase*DK;
  const unsigned short* krow = kH + tokBase*DK;
  const float bv = beta[tokBase + w*16 + lo];

  // stage vT = vb^T (all vbH reads complete before first barrier)
  {
    const int r = tid >> 2, cs = (tid & 3) * 64;
    const unsigned short* vrow = vbH + (tokBase + r)*DK + cs;
    bf16x8 vv[8];
    #pragma unroll
    for (int j=0;j<8;j++) vv[j] = *(const bf16x8*)(vrow + j*8);
    #pragma unroll
    for (int j=0;j<8;j++)
      #pragma unroll
      for (int e=0;e<8;e++)
        vT[(cs + j*8 + e)*72 + r] = (unsigned short)vv[j][e];
  }

  // M = Kb K^T (strict lower), attn = tril(Q K^T)
  f32x4 mAcc[4] = {}; f32x4 aAcc[4] = {};
  #pragma unroll
  for (int ks=0; ks<8; ks++){
    bf16x8 kf[4];
    #pragma unroll
    for (int nt=0; nt<4; nt++)
      kf[nt] = *(const bf16x8*)&krow[(nt*16+lo)*DK + ks*32 + quad*8];
    bf16x8 qf  = *(const bf16x8*)&qrow[(w*16+lo)*DK + ks*32 + quad*8];
    bf16x8 kfw = *(const bf16x8*)&krow[(w*16+lo)*DK + ks*32 + quad*8];
    bf16x8 kbf;
    #pragma unroll
    for (int j=0;j<8;j++) kbf[j] = (short)f2bf(bf2f((unsigned short)kfw[j]) * bv);
    #pragma unroll
    for (int nt=0; nt<4; nt++){
      mAcc[nt] = MFMA(kbf, kf[nt], mAcc[nt]);
      aAcc[nt] = MFMA(qf,  kf[nt], aAcc[nt]);
    }
  }
  unsigned short* Ap = Aout + ((long)bh*NCHUNK + c)*64*64;
  #pragma unroll
  for (int nt=0; nt<4; nt++)
    #pragma unroll
    for (int r=0; r<4; r++){
      int t = w*16 + quad*4 + r, s = nt*16 + lo;
      float mv = (t > s) ? mAcc[nt][r] : 0.f;
      unsigned short mb = f2bf(mv);
      Nn[t*72+s] = mb;
      NT[s*72+t] = mb;
      Pb[t*72+s] = f2bf((t==s ? 1.f : 0.f) - mv);
      Ap[t*64+s] = f2bf((t >= s) ? aAcc[nt][r] : 0.f);
    }
  __syncthreads();

  // (I+N)^-1 = (I-N)(I+N^2)(I+N^4)(I+N^8)(I+N^16)(I+N^32); single-buffered w/ reg prefetch
  #pragma unroll 1
  for (int it=0; it<5; it++){
    bf16x8 aN[2], aP[2], bN[2][4];
    #pragma unroll
    for (int ks=0; ks<2; ks++){
      aN[ks] = *(const bf16x8*)&Nn[(w*16+lo)*72 + ks*32 + quad*8];
      aP[ks] = *(const bf16x8*)&Pb[(w*16+lo)*72 + ks*32 + quad*8];
      #pragma unroll
      for (int nt=0; nt<4; nt++)
        bN[ks][nt] = *(const bf16x8*)&NT[(nt*16+lo)*72 + ks*32 + quad*8];
    }
    f32x4 pp[4];
    #pragma unroll
    for (int nt=0; nt<4; nt++)
      #pragma unroll
      for (int r=0; r<4; r++)
        pp[nt][r] = bf2f(Pb[(w*16+quad*4+r)*72 + nt*16+lo]);
    __syncthreads();                     // all reads of cur done
    f32x4 sq[4] = {};
    #pragma unroll
    for (int ks=0; ks<2; ks++)
      #pragma unroll
      for (int nt=0; nt<4; nt++)
        sq[nt] = MFMA(aN[ks], bN[ks][nt], sq[nt]);
    #pragma unroll
    for (int nt=0; nt<4; nt++)
      #pragma unroll
      for (int r=0; r<4; r++){
        int t = w*16 + quad*4 + r, s = nt*16 + lo;
        unsigned short vb2 = f2bf(sq[nt][r]);
        Nn[t*72+s] = vb2; NT[s*72+t] = vb2;
      }
    __syncthreads();                     // N^2 visible
    #pragma unroll
    for (int ks=0; ks<2; ks++)
      #pragma unroll
      for (int nt=0; nt<4; nt++){
        bf16x8 b = *(const bf16x8*)&NT[(nt*16+lo)*72 + ks*32 + quad*8];
        pp[nt] = MFMA(aP[ks], b, pp[nt]);
      }
    #pragma unroll
    for (int nt=0; nt<4; nt++)
      #pragma unroll
      for (int r=0; r<4; r++)
        Pb[(w*16+quad*4+r)*72 + nt*16+lo] = f2bf(pp[nt][r]);
    __syncthreads();                     // P_next visible
  }

  // W = T*Kb (B from chunk-tiled kT rows, beta-scaled inline), U = T*Vb (B from vT LDS)
  float b8[2][8];
  #pragma unroll
  for (int ks=0; ks<2; ks++)
    #pragma unroll
    for (int e=0; e<8; e++)
      b8[ks][e] = beta[tokBase + ks*32 + quad*8 + e];
  const unsigned short* kTb = kT + ((long)bh*NCHUNK + c)*DK*64;
  unsigned short* Wp = Wout + tokBase*DK;
  unsigned short* Up = Uout + tokBase*DK;
  #pragma unroll 1
  for (int nl=0; nl<4; nl++){
    const int d = (w*4 + nl)*16 + lo;
    f32x4 wa[4] = {}; f32x4 ua[4] = {};
    #pragma unroll
    for (int ks=0; ks<2; ks++){
      bf16x8 braw = *(const bf16x8*)&kTb[(long)d*64 + ks*32 + quad*8];
      bf16x8 bw;
      #pragma unroll
      for (int e=0; e<8; e++) bw[e] = (short)f2bf(bf2f((unsigned short)braw[e]) * b8[ks][e]);
      bf16x8 bu = *(const bf16x8*)&vT[d*72 + ks*32 + quad*8];
      #pragma unroll
      for (int mt=0; mt<4; mt++){
        bf16x8 a = *(const bf16x8*)&Pb[(mt*16+lo)*72 + ks*32 + quad*8];
        wa[mt] = MFMA(a, bw, wa[mt]);
        ua[mt] = MFMA(a, bu, ua[mt]);
      }
    }
    #pragma unroll
    for (int mt=0; mt<4; mt++)
      #pragma unroll
      for (int r=0; r<4; r++){
        int t = mt*16 + quad*4 + r;
        Wp[t*DK + d] = f2bf(wa[mt][r]);
        Up[t*DK + d] = f2bf(ua[mt][r]);
      }
  }
}

// ---------------- sequential chunk scan: SINGLE-WAVE blocks, zero barriers ----------------
// 256 streams (16 bh x 16 v-slices) = 256 CUs, one 64-lane wave each. The wave
// does all 4 t-blocks and all 16 d-blocks itself: no cross-wave exchange, so no
// __syncthreads and no vmcnt-drain per chunk (the round-4 bottleneck: 2 drains x
// 64 chunks ~ 5-6 kcy/chunk of stall). LDS write->read within the wave is ordered
// by compiler-inserted lgkmcnt. Same fragment layouts and accumulation order as
// the verified 4-wave version (bitwise-identical rounding).
__device__ __forceinline__ int sidx(int n, int d){       // S_l [16][256] swizzled
  return n*256 + (((d>>3) ^ (n&7))<<3) + (d&7);
}
__device__ __forceinline__ int uidx(int n, int t){       // u_l [16][64] swizzled
  return n*64 + ((((t>>3) ^ (n&7)) & 7)<<3) + (t&7);
}

__global__ __launch_bounds__(64,1) void k_scan(
  const unsigned short* __restrict__ Wm, const unsigned short* __restrict__ Um,
  const unsigned short* __restrict__ qH, const unsigned short* __restrict__ kT,
  const unsigned short* __restrict__ Abuf, unsigned short* __restrict__ oH)
{
  const int bh = blockIdx.x, vb = blockIdx.y;
  __shared__ unsigned short S_l[DVS*256];   // 8 KiB, bf16 mirror of state [n][d]
  __shared__ unsigned short u_l[DVS*64];    // 2 KiB, u_new^T [n][t]
  const int l = threadIdx.x & 63, lo = l & 15, quad = l >> 4;
  for (int i = l; i < DVS*256/4; i += 64) ((unsigned long long*)S_l)[i] = 0ULL;
  f32x4 S[16] = {};                         // f32 master: frag mtl = d rows mtl*16+quad*4+r, col lo
  const long hb = (long)bh * LDIM;
  const unsigned short* Wp  = Wm + hb*DK;
  const unsigned short* Up  = Um + hb*DK;
  const unsigned short* qp  = qH + hb*DK;
  const unsigned short* kTp = kT + (long)bh*NCHUNK*DK*64;
  const unsigned short* Ap  = Abuf + (long)bh*NCHUNK*64*64;
  unsigned short* op = oH + hb*DK;

  #pragma unroll 1
  for (int c = 0; c < NCHUNK; ++c){
    const unsigned short* Wc = Wp + (long)c*64*DK;
    const unsigned short* Uc = Up + (long)c*64*DK;
    const unsigned short* qc = qp + (long)c*64*DK;
    const unsigned short* Ac = Ap + (long)c*64*64;
    const unsigned short* kc = kTp + (long)c*DK*64;   // chunk-tiled [256][64]

    // S fragments once per chunk (B-operand: n=lo, k=d-slice); reused in A and B
    bf16x8 sb[8];
    #pragma unroll
    for (int ks=0; ks<8; ks++)
      sb[ks] = *(const bf16x8*)&S_l[sidx(lo, ks*32+quad*8)];

    // phase A: u_new = U - W*S, all 4 t-blocks
    #pragma unroll
    for (int mt=0; mt<4; mt++){
      bf16x8 wf[8];
      #pragma unroll
      for (int ks=0; ks<8; ks++)
        wf[ks] = *(const bf16x8*)&Wc[(mt*16+lo)*DK + ks*32 + quad*8];
      unsigned short uf[4];
      #pragma unroll
      for (int r=0; r<4; r++)
        uf[r] = Uc[(mt*16+quad*4+r)*DK + vb*DVS + lo];
      f32x4 a0 = {}, a1 = {};
      #pragma unroll
      for (int ks=0; ks<4; ks++){
        a0 = MFMA(wf[ks],   sb[ks],   a0);
        a1 = MFMA(wf[ks+4], sb[ks+4], a1);
      }
      ushort4 pk;
      pk.x = f2bf(bf2f(uf[0]) - (a0[0]+a1[0]));
      pk.y = f2bf(bf2f(uf[1]) - (a0[1]+a1[1]));
      pk.z = f2bf(bf2f(uf[2]) - (a0[2]+a1[2]));
      pk.w = f2bf(bf2f(uf[3]) - (a0[3]+a1[3]));
      *(ushort4*)&u_l[uidx(lo, mt*16+quad*4)] = pk;
    }

    // u fragments (B-operand: n=lo, k=t-slice); lgkmcnt orders vs writes above
    bf16x8 ub[2];
    #pragma unroll
    for (int ks=0; ks<2; ks++)
      ub[ks] = *(const bf16x8*)&u_l[uidx(lo, ks*32+quad*8)];

    // phase B: o = q*S + attn*u_new, all 4 t-blocks
    #pragma unroll
    for (int mt=0; mt<4; mt++){
      bf16x8 qf[8], af[2];
      #pragma unroll
      for (int ks=0; ks<8; ks++)
        qf[ks] = *(const bf16x8*)&qc[(mt*16+lo)*DK + ks*32 + quad*8];
      #pragma unroll
      for (int ks=0; ks<2; ks++)
        af[ks] = *(const bf16x8*)&Ac[(mt*16+lo)*64 + ks*32 + quad*8];
      f32x4 o0 = {}, o1 = {};
      #pragma unroll
      for (int ks=0; ks<4; ks++){
        o0 = MFMA(qf[ks],   sb[ks],   o0);
        o1 = MFMA(qf[ks+4], sb[ks+4], o1);
      }
      #pragma unroll
      for (int ks=0; ks<2; ks++)
        o0 = MFMA(af[ks], ub[ks], o0);
      #pragma unroll
      for (int r=0; r<4; r++)
        op[(long)(c*64 + mt*16 + quad*4 + r)*DK + vb*DVS + lo] = f2bf(o0[r] + o1[r]);
    }

    // phase C: S += k^T * u_new, all 16 d-blocks; refresh S_l
    #pragma unroll
    for (int mtl=0; mtl<16; mtl++){
      bf16x8 k0 = *(const bf16x8*)&kc[(mtl*16+lo)*64 + 0*32 + quad*8];
      bf16x8 k1 = *(const bf16x8*)&kc[(mtl*16+lo)*64 + 1*32 + quad*8];
      S[mtl] = MFMA(k0, ub[0], S[mtl]);
      S[mtl] = MFMA(k1, ub[1], S[mtl]);
      const int d0 = mtl*16 + quad*4;
      ushort4 pk;
      pk.x = f2bf(S[mtl][0]); pk.y = f2bf(S[mtl][1]);
      pk.z = f2bf(S[mtl][2]); pk.w = f2bf(S[mtl][3]);
      *(ushort4*)&S_l[sidx(lo, d0)] = pk;
    }
  }
}

// ---------------- per-head RMSNorm * g, to [B,L,D] bf16 ----------------
__global__ __launch_bounds__(64) void k_rms(
  const unsigned short* __restrict__ oH, const float* __restrict__ g,
  unsigned short* __restrict__ oN)
{
  const int ln = blockIdx.x, bh = blockIdx.y;
  const int b = bh >> 3, h = bh & 7;
  ushort4 u = *(const ushort4*)(oH + ((long)bh*LDIM + ln)*DK + threadIdx.x*4);
  float4 v; v.x = bf2f(u.x); v.y = bf2f(u.y); v.z = bf2f(u.z); v.w = bf2f(u.w);
  float ss = v.x*v.x + v.y*v.y + v.z*v.z + v.w*v.w;
  #pragma unroll
  for (int off=32; off; off>>=1) ss += __shfl_down(ss, off, 64);
  ss = __shfl(ss, 0, 64);
  const float sc = rsqrtf(ss*(1.f/DK) + 1e-5f);
  const float4 gv = *(const float4*)(g + threadIdx.x*4);
  unsigned short* o = oN + ((long)b*LDIM + ln)*DDIM + h*DK + threadIdx.x*4;
  ushort4 pk; pk.x=f2bf(v.x*sc*gv.x); pk.y=f2bf(v.y*sc*gv.y);
  pk.z=f2bf(v.z*sc*gv.z); pk.w=f2bf(v.w*sc*gv.w);
  *(ushort4*)o = pk;
}

extern "C" void kernel_launch(void* const* d_in, const int* in_sizes, int n_in,
                              void* d_out, int out_size, void* d_ws, size_t ws_size,
                              hipStream_t stream)
{
  (void)in_sizes; (void)n_in; (void)out_size;
  const float* hs = (const float*)d_in[0];
  const float* Wq = (const float*)d_in[1];
  const float* Wk = (const float*)d_in[2];
  const float* Wv = (const float*)d_in[3];
  const float* Wb = (const float*)d_in[4];
  const float* cq = (const float*)d_in[5];
  const float* ck = (const float*)d_in[6];
  const float* cv = (const float*)d_in[7];
  const float* gn = (const float*)d_in[8];
  const float* Wo = (const float*)d_in[9];

  // Workspace plan:
  //  A 32MiB: hs_bf [cast..gemmV]          -> U    [passA..scan]
  //  B  8MiB: weight bf16 (Wq->Wk->Wv->Wo, recast sequentially)
  //  C 32MiB: pre [gemm..conv]x3 -> kT chunk-tiled [transpose..scan] -> o_norm [rms..gemmO]
  //  D 32MiB: q_head [convQ..scan]
  //  E 32MiB: k_head [convK..passA]        -> o bf16 [scan..rms]
  //  F 32MiB: v*beta [convV..passA]
  //  G  8MiB: attn tiles [passA..scan]
  //  H 256KiB: beta
  //  W 32MiB: W buffer (if ws allows; else W written in-place over F)
  const size_t SZ_TD2 = (size_t)TOK*DDIM*2;      // 32 MiB
  const size_t SZ_DD2 = (size_t)DDIM*DDIM*2;     //  8 MiB
  const size_t NEED  = 5*SZ_TD2 + 2*SZ_DD2 + (size_t)NBH*LDIM*4;
  const size_t NEEDW = NEED + SZ_TD2;
  if (ws_size < NEED){ k_guard<<<1, 64, 0, stream>>>((float*)d_out); return; }

  char* p = (char*)d_ws;
  unsigned short* bufA = (unsigned short*)p;      p += SZ_TD2;   // hs_bf / U
  unsigned short* bufB = (unsigned short*)p;      p += SZ_DD2;   // weights
  unsigned short* bufC = (unsigned short*)p;      p += SZ_TD2;   // pre / kT / o_norm
  unsigned short* bufD = (unsigned short*)p;      p += SZ_TD2;   // q_head
  unsigned short* bufE = (unsigned short*)p;      p += SZ_TD2;   // k_head / o
  unsigned short* bufF = (unsigned short*)p;      p += SZ_TD2;   // v*beta (/W fallback)
  unsigned short* bufG = (unsigned short*)p;      p += SZ_DD2;   // attn (8 MiB exactly)
  float*          beta = (float*)p;               p += (size_t)NBH*LDIM*4;
  unsigned short* bufW = (ws_size >= NEEDW) ? (unsigned short*)p : bufF;

  const dim3 gg(DDIM/128, TOK/128);
  const dim3 cg(LDIM/64, NBH);
  const int nTD = TOK*DDIM, nDD = DDIM*DDIM;

  k_f2bf<<<dim3(nTD/1024), 256, 0, stream>>>(hs, bufA, nTD);
  k_beta<<<dim3(TOK), 256, 0, stream>>>(hs, Wb, beta);

  k_f2bf<<<dim3(nDD/1024), 256, 0, stream>>>(Wq, bufB, nDD);
  k_gemm_bt<false><<<gg, 256, 0, stream>>>(bufA, bufB, bufC, TOK, DDIM, DDIM);
  k_conv<<<cg, 256, 0, stream>>>(bufC, cq, beta, bufD, 0);

  k_f2bf<<<dim3(nDD/1024), 256, 0, stream>>>(Wk, bufB, nDD);
  k_gemm_bt<false><<<gg, 256, 0, stream>>>(bufA, bufB, bufC, TOK, DDIM, DDIM);
  k_conv<<<cg, 256, 0, stream>>>(bufC, ck, beta, bufE, 1);

  k_f2bf<<<dim3(nDD/1024), 256, 0, stream>>>(Wv, bufB, nDD);
  k_gemm_bt<false><<<gg, 256, 0, stream>>>(bufA, bufB, bufC, TOK, DDIM, DDIM);
  k_conv<<<cg, 256, 0, stream>>>(bufC, cv, beta, bufF, 2);

  k_transpose<<<dim3(LDIM/64, DK/64, NBH), 256, 0, stream>>>(bufE, bufC);      // kT -> C
  k_passA<<<dim3(NCHUNK, NBH), 256, 0, stream>>>(bufD, bufE, bufF, bufC, beta,
                                                 bufW, bufA /*U*/, bufG);
  k_scan<<<dim3(NBH, 16), 64, 0, stream>>>(bufW, bufA, bufD, bufC, bufG, bufE); // o -> E
  k_rms<<<dim3(LDIM, NBH), 64, 0, stream>>>(bufE, gn, bufC);                     // o_norm -> C

  k_f2bf<<<dim3(nDD/1024), 256, 0, stream>>>(Wo, bufB, nDD);
  k_gemm_bt<true><<<gg, 256, 0, stream>>>(bufC, bufB, d_out /*f32*/, TOK, DDIM, DDIM);
}

// Round 6
// 868.429 us; speedup vs baseline: 2.0170x; 2.0170x over previous
//
#include <hip/hip_runtime.h>
#include <stdint.h>

#define TOK    8192   // B*L
#define LDIM   4096
#define DDIM   2048
#define NBH    16     // B*H
#define DK     256
#define NCHUNK 64
#define DVS    16     // v-slice width per scan block

typedef __attribute__((ext_vector_type(8))) short bf16x8;   // 8 bf16 (4 VGPRs)
typedef __attribute__((ext_vector_type(4))) float f32x4;

#define MFMA(a,b,c) __builtin_amdgcn_mfma_f32_16x16x32_bf16((a),(b),(c),0,0,0)

__device__ __forceinline__ unsigned short f2bf(float f){
  union { float f; uint32_t u; } v; v.f = f;
  uint32_t r = v.u + 0x7FFFu + ((v.u >> 16) & 1u);   // RNE
  return (unsigned short)(r >> 16);
}
__device__ __forceinline__ float bf2f(unsigned short u){
  union { uint32_t u; float f; } v; v.u = ((uint32_t)u) << 16;
  return v.f;
}

typedef __attribute__((address_space(1))) unsigned int as1_u32;
typedef __attribute__((address_space(3))) unsigned int as3_u32;
__device__ __forceinline__ void gload16(const void* g, void* l){
  __builtin_amdgcn_global_load_lds((const as1_u32*)g, (as3_u32*)l, 16, 0, 0);
}

// LDS-only barrier: waits all my DS ops (lgkmcnt) then barriers, WITHOUT draining
// vmcnt — global_load_lds prefetches stay in flight across it (T3/T4 mechanism).
__device__ __forceinline__ void bar_lds(){
  asm volatile("s_waitcnt lgkmcnt(0)\n\ts_barrier" ::: "memory");
}

// ---------------- guard (ws too small): clean fail, non-empty graph ----------------
__global__ void k_guard(float* o){ if (threadIdx.x == 0) o[0] = 0.f; }

// ---------------- f32 -> bf16 cast ----------------
__global__ __launch_bounds__(256) void k_f2bf(const float* __restrict__ s,
                                              unsigned short* __restrict__ d, int n)
{
  int i = (blockIdx.x*256 + threadIdx.x)*4;
  if (i >= n) return;
  float4 v = *(const float4*)(s + i);
  ushort4 o; o.x=f2bf(v.x); o.y=f2bf(v.y); o.z=f2bf(v.z); o.w=f2bf(v.w);
  *(ushort4*)(d + i) = o;
}

// ---------------- beta = sigmoid(hs @ Wb^T), [bh][l] ----------------
__global__ __launch_bounds__(256) void k_beta(const float* __restrict__ hs,
                                              const float* __restrict__ Wb,
                                              float* __restrict__ beta)
{
  const long t = blockIdx.x;          // token
  const int tid = threadIdx.x;
  float acc[8] = {0,0,0,0,0,0,0,0};
  const float* xr = hs + t*DDIM;
  for (int i = tid; i < DDIM; i += 256){
    float x = xr[i];
    #pragma unroll
    for (int h=0; h<8; h++) acc[h] += x * Wb[h*DDIM + i];
  }
  __shared__ float red[8][4];
  const int w = tid >> 6, lane = tid & 63;
  #pragma unroll
  for (int h=0; h<8; h++){
    float s = acc[h];
    #pragma unroll
    for (int off=32; off; off>>=1) s += __shfl_down(s, off, 64);
    if (lane == 0) red[h][w] = s;
  }
  __syncthreads();
  if (tid < 8){
    float s = red[tid][0]+red[tid][1]+red[tid][2]+red[tid][3];
    float bv = 1.f/(1.f + __expf(-s));
    int b = (int)(t >> 12), l = (int)(t & 4095);
    beta[((long)(b*8 + tid))*LDIM + l] = bv;
  }
}

// ---------------- GEMM 256x256 tile, BK=32, 4-deep LDS ring, counted vmcnt ----------------
// C[M,N] = A[M,K] * B[N,K]^T, bf16 in, bf16 or f32 out.
// T2: bank-swizzle via inverse-XOR'd GLOBAL source col (linear gload_lds dest) +
//     same XOR on ds_read (rule #21). swz: colB ^= ((row&3)<<4) within 64B row.
// T3/T4: stage tile t+2 while computing tile t; vmcnt(8) steady state (never 0);
//        one lgkm-only barrier per K-tile. Ring distance 2 => stage target never
//        collides with tile t (current reads) or tile t-1 (laggard waves' reads,
//        complete before their barrier via lgkmcnt(0)).
template <bool F32OUT>
__global__ __launch_bounds__(512) void k_gemm256(
    const unsigned short* __restrict__ A, const unsigned short* __restrict__ Bw,
    void* __restrict__ Cv, int M, int N, int K)
{
  __shared__ unsigned short As[4][256*32];   // 4 x 16 KiB
  __shared__ unsigned short Bs[4][256*32];   // 4 x 16 KiB  (128 KiB total)
  const int tid = threadIdx.x;
  const int w = tid >> 6, l = tid & 63;
  const int lo = l & 15, quad = l >> 4;
  const int wm = w >> 2, wn = w & 3;         // 2 x 4 waves, per-wave 128x64 out
  // T1: XCD-aware bijective block swizzle (nwg % 8 == 0 here)
  const int gx = gridDim.x;
  int id = blockIdx.y * gx + blockIdx.x;
  const int nwg = gx * gridDim.y;
  if ((nwg & 7) == 0){ const int q8 = nwg >> 3; id = (id & 7)*q8 + (id >> 3); }
  const int bx = id % gx, by = id / gx;
  const long tm = (long)by * 256, tn = (long)bx * 256;

  // staging: 1024 slots of 16B per matrix per tile; thread -> slots (w*2+j)*64+l
  // LDS linear byte o = slot*16; row = slot>>2; colB = (slot&3)*16;
  // global source col-bytes = colB ^ ((row&3)<<4)   (inverse swizzle)
  const int slot0 = (w*2+0)*64 + l;
  const int slot1 = (w*2+1)*64 + l;
  const int r0 = slot0 >> 2, c0 = ((slot0 & 3)*16) ^ ((r0 & 3) << 4);
  const int r1 = slot1 >> 2, c1 = ((slot1 & 3)*16) ^ ((r1 & 3) << 4);
  const unsigned short* pA0 = A  + (tm + r0)*(long)K + (c0 >> 1);
  const unsigned short* pA1 = A  + (tm + r1)*(long)K + (c1 >> 1);
  const unsigned short* pB0 = Bw + (tn + r0)*(long)K + (c0 >> 1);
  const unsigned short* pB1 = Bw + (tn + r1)*(long)K + (c1 >> 1);
  // ds_read swizzled col offset (shorts): quad*16B ^ ((row&3)<<4), row&3 == lo&3
  const int asw = ((quad*16) ^ ((lo & 3) << 4)) >> 1;

  f32x4 acc[8][4] = {};
  const int nt = K >> 5;                     // K-tiles of 32 (nt >= 3)

#define STAGE(t_) do { const int kk_ = (t_)*32, b_ = (t_) & 3;      \
    gload16(pA0 + kk_, &As[b_][slot0*8]);                           \
    gload16(pA1 + kk_, &As[b_][slot1*8]);                           \
    gload16(pB0 + kk_, &Bs[b_][slot0*8]);                           \
    gload16(pB1 + kk_, &Bs[b_][slot1*8]); } while(0)

#define COMPUTE(t_) do { const int b_ = (t_) & 3;                              \
    bf16x8 af[8], bg[4];                                                       \
    _Pragma("unroll")                                                          \
    for (int mf=0; mf<8; mf++)                                                 \
      af[mf] = *(const bf16x8*)&As[b_][(wm*128 + mf*16 + lo)*32 + asw];        \
    _Pragma("unroll")                                                          \
    for (int nf=0; nf<4; nf++)                                                 \
      bg[nf] = *(const bf16x8*)&Bs[b_][(wn*64 + nf*16 + lo)*32 + asw];         \
    _Pragma("unroll")                                                          \
    for (int mf=0; mf<8; mf++)                                                 \
      _Pragma("unroll")                                                        \
      for (int nf=0; nf<4; nf++)                                               \
        acc[mf][nf] = MFMA(af[mf], bg[nf], acc[mf][nf]); } while(0)

  STAGE(0); STAGE(1);
  #pragma unroll 1
  for (int t = 0; t < nt-2; ++t){
    STAGE(t+2);                                        // 2 tiles ahead
    asm volatile("s_waitcnt vmcnt(8)" ::: "memory");   // wait tile t only
    bar_lds();
    COMPUTE(t);
  }
  asm volatile("s_waitcnt vmcnt(4)" ::: "memory");
  bar_lds();
  COMPUTE(nt-2);
  asm volatile("s_waitcnt vmcnt(0)" ::: "memory");
  bar_lds();
  COMPUTE(nt-1);
#undef STAGE
#undef COMPUTE

  #pragma unroll
  for (int mf=0; mf<8; mf++)
    #pragma unroll
    for (int nf=0; nf<4; nf++)
      #pragma unroll
      for (int r=0; r<4; r++){
        long m = tm + wm*128 + mf*16 + quad*4 + r;
        long n = tn + wn*64 + nf*16 + lo;
        if (F32OUT) ((float*)Cv)[m*N + n] = acc[mf][nf][r];
        else ((unsigned short*)Cv)[m*N + n] = f2bf(acc[mf][nf][r]);
      }
}

// ---------------- causal conv(K=4)+silu (+l2norm q/k, *beta for v), head layout out ----------------
// mode: 0=q (l2norm + dk^-0.5), 1=k (l2norm), 2=v (silu * beta)
__global__ __launch_bounds__(256) void k_conv(
  const unsigned short* __restrict__ X, const float* __restrict__ Wc,
  const float* __restrict__ beta,
  unsigned short* __restrict__ O, int mode)
{
  const int lt = blockIdx.x, bh = blockIdx.y;
  const int b = bh >> 3, h = bh & 7;
  const int d = threadIdx.x;                 // 0..255 within head
  const int ch = h*256 + d;
  const int l0 = lt*64;
  const unsigned short* xp = X + (long)b*LDIM*DDIM + ch;
  const float4 wv = *(const float4*)(Wc + ch*4);
  float x0=0.f, x1=0.f, x2=0.f;
  if (l0 >= 3){
    x0 = bf2f(xp[(long)(l0-3)*DDIM]);
    x1 = bf2f(xp[(long)(l0-2)*DDIM]);
    x2 = bf2f(xp[(long)(l0-1)*DDIM]);
  }
  float y[64];
  #pragma unroll
  for (int i=0;i<64;i++){
    float x3 = bf2f(xp[(long)(l0+i)*DDIM]);
    float s = x0*wv.x + x1*wv.y + x2*wv.z + x3*wv.w;
    y[i] = s / (1.f + __expf(-s));
    x0 = x1; x1 = x2; x2 = x3;
  }
  unsigned short* op = O + (long)bh*LDIM*DK + d;
  if (mode == 2){
    const float* bet = beta + (long)bh*LDIM + l0;
    #pragma unroll
    for (int i=0;i<64;i++) op[(long)(l0+i)*DK] = f2bf(y[i]*bet[i]);
    return;
  }
  __shared__ float red[64*4];
  __shared__ float scl[64];
  const int wv_i = threadIdx.x >> 6, lane = threadIdx.x & 63;
  #pragma unroll
  for (int i=0;i<64;i++){
    float ss = y[i]*y[i];
    #pragma unroll
    for (int off=32; off; off>>=1) ss += __shfl_down(ss, off, 64);
    if (lane == 0) red[i*4 + wv_i] = ss;
  }
  __syncthreads();
  if (threadIdx.x < 64){
    int i = threadIdx.x;
    float s = red[i*4]+red[i*4+1]+red[i*4+2]+red[i*4+3];
    scl[i] = rsqrtf(s + 1e-6f) * (mode==0 ? 0.0625f : 1.f);   // dk^-0.5 folded into q
  }
  __syncthreads();
  #pragma unroll
  for (int i=0;i<64;i++) op[(long)(l0+i)*DK] = f2bf(y[i]*scl[i]);
}

// ---------------- transpose k: CHUNK-TILED kT[bh][c][d][64] (rows 128B) ----------------
__global__ __launch_bounds__(256) void k_transpose(
  const unsigned short* __restrict__ kH, unsigned short* __restrict__ kT)
{
  const int lt = blockIdx.x, dt = blockIdx.y, bh = blockIdx.z;
  __shared__ unsigned short tk[64][72];   // 144B rows, 16B aligned
  const int tid = threadIdx.x;
  const int rl = tid >> 2, c0 = (tid & 3) * 16;
  const long base = ((long)bh*LDIM + lt*64 + rl)*DK + dt*64 + c0;
  *(bf16x8*)&tk[rl][c0]   = *(const bf16x8*)(kH + base);
  *(bf16x8*)&tk[rl][c0+8] = *(const bf16x8*)(kH + base + 8);
  __syncthreads();
  const int rd = tid >> 2, lc0 = (tid & 3) * 16;
  bf16x8 ok0, ok1;
  #pragma unroll
  for (int j=0;j<16;j++){
    unsigned short kraw = tk[lc0+j][rd];
    if (j < 8) ok0[j] = (short)kraw; else ok1[j-8] = (short)kraw;
  }
  const long ob = (((long)bh*NCHUNK + lt)*DK + dt*64 + rd)*64 + lc0;
  *(bf16x8*)(kT + ob) = ok0; *(bf16x8*)(kT + ob + 8) = ok1;
}

// ---------------- pass A: per (bh,chunk) attn, T=(I+M)^-1 (Neumann product), W=T*Kb, U=T*Vb ----------------
__global__ __launch_bounds__(256) void k_passA(
  const unsigned short* __restrict__ qH, const unsigned short* __restrict__ kH,
  const unsigned short* vbH,            // v*beta [bh][l][dk] (may alias Wout in fallback)
  const unsigned short* __restrict__ kT,
  const float* __restrict__ beta,
  unsigned short* Wout,
  unsigned short* __restrict__ Uout,
  unsigned short* __restrict__ Aout)
{
  const int c = blockIdx.x, bh = blockIdx.y;
  __shared__ unsigned short Nn[64*72];
  __shared__ unsigned short NT[64*72];
  __shared__ unsigned short Pb[64*72];
  __shared__ unsigned short vT[256*72];   // vb^T [d][s], stride 72 (63KiB total)
  const int tid = threadIdx.x;
  const int w = tid >> 6, l = tid & 63, lo = l & 15, quad = l >> 4;
  const long tokBase = (long)bh*LDIM + c*64;
  const unsigned short* qrow = qH + tokBase*DK;
  const unsigned short* krow = kH + tokBase*DK;
  const float bv = beta[tokBase + w*16 + lo];

  // stage vT = vb^T (all vbH reads complete before first barrier)
  {
    const int r = tid >> 2, cs = (tid & 3) * 64;
    const unsigned short* vrow = vbH + (tokBase + r)*DK + cs;
    bf16x8 vv[8];
    #pragma unroll
    for (int j=0;j<8;j++) vv[j] = *(const bf16x8*)(vrow + j*8);
    #pragma unroll
    for (int j=0;j<8;j++)
      #pragma unroll
      for (int e=0;e<8;e++)
        vT[(cs + j*8 + e)*72 + r] = (unsigned short)vv[j][e];
  }

  // M = Kb K^T (strict lower), attn = tril(Q K^T)
  f32x4 mAcc[4] = {}; f32x4 aAcc[4] = {};
  #pragma unroll
  for (int ks=0; ks<8; ks++){
    bf16x8 kf[4];
    #pragma unroll
    for (int nt=0; nt<4; nt++)
      kf[nt] = *(const bf16x8*)&krow[(nt*16+lo)*DK + ks*32 + quad*8];
    bf16x8 qf  = *(const bf16x8*)&qrow[(w*16+lo)*DK + ks*32 + quad*8];
    bf16x8 kfw = *(const bf16x8*)&krow[(w*16+lo)*DK + ks*32 + quad*8];
    bf16x8 kbf;
    #pragma unroll
    for (int j=0;j<8;j++) kbf[j] = (short)f2bf(bf2f((unsigned short)kfw[j]) * bv);
    #pragma unroll
    for (int nt=0; nt<4; nt++){
      mAcc[nt] = MFMA(kbf, kf[nt], mAcc[nt]);
      aAcc[nt] = MFMA(qf,  kf[nt], aAcc[nt]);
    }
  }
  unsigned short* Ap = Aout + ((long)bh*NCHUNK + c)*64*64;
  #pragma unroll
  for (int nt=0; nt<4; nt++)
    #pragma unroll
    for (int r=0; r<4; r++){
      int t = w*16 + quad*4 + r, s = nt*16 + lo;
      float mv = (t > s) ? mAcc[nt][r] : 0.f;
      unsigned short mb = f2bf(mv);
      Nn[t*72+s] = mb;
      NT[s*72+t] = mb;
      Pb[t*72+s] = f2bf((t==s ? 1.f : 0.f) - mv);
      Ap[t*64+s] = f2bf((t >= s) ? aAcc[nt][r] : 0.f);
    }
  __syncthreads();

  // (I+N)^-1 = (I-N)(I+N^2)(I+N^4)(I+N^8)(I+N^16)(I+N^32); single-buffered w/ reg prefetch
  #pragma unroll 1
  for (int it=0; it<5; it++){
    bf16x8 aN[2], aP[2], bN[2][4];
    #pragma unroll
    for (int ks=0; ks<2; ks++){
      aN[ks] = *(const bf16x8*)&Nn[(w*16+lo)*72 + ks*32 + quad*8];
      aP[ks] = *(const bf16x8*)&Pb[(w*16+lo)*72 + ks*32 + quad*8];
      #pragma unroll
      for (int nt=0; nt<4; nt++)
        bN[ks][nt] = *(const bf16x8*)&NT[(nt*16+lo)*72 + ks*32 + quad*8];
    }
    f32x4 pp[4];
    #pragma unroll
    for (int nt=0; nt<4; nt++)
      #pragma unroll
      for (int r=0; r<4; r++)
        pp[nt][r] = bf2f(Pb[(w*16+quad*4+r)*72 + nt*16+lo]);
    __syncthreads();                     // all reads of cur done
    f32x4 sq[4] = {};
    #pragma unroll
    for (int ks=0; ks<2; ks++)
      #pragma unroll
      for (int nt=0; nt<4; nt++)
        sq[nt] = MFMA(aN[ks], bN[ks][nt], sq[nt]);
    #pragma unroll
    for (int nt=0; nt<4; nt++)
      #pragma unroll
      for (int r=0; r<4; r++){
        int t = w*16 + quad*4 + r, s = nt*16 + lo;
        unsigned short vb2 = f2bf(sq[nt][r]);
        Nn[t*72+s] = vb2; NT[s*72+t] = vb2;
      }
    __syncthreads();                     // N^2 visible
    #pragma unroll
    for (int ks=0; ks<2; ks++)
      #pragma unroll
      for (int nt=0; nt<4; nt++){
        bf16x8 b = *(const bf16x8*)&NT[(nt*16+lo)*72 + ks*32 + quad*8];
        pp[nt] = MFMA(aP[ks], b, pp[nt]);
      }
    #pragma unroll
    for (int nt=0; nt<4; nt++)
      #pragma unroll
      for (int r=0; r<4; r++)
        Pb[(w*16+quad*4+r)*72 + nt*16+lo] = f2bf(pp[nt][r]);
    __syncthreads();                     // P_next visible
  }

  // W = T*Kb (B from chunk-tiled kT rows, beta-scaled inline), U = T*Vb (B from vT LDS)
  float b8[2][8];
  #pragma unroll
  for (int ks=0; ks<2; ks++)
    #pragma unroll
    for (int e=0; e<8; e++)
      b8[ks][e] = beta[tokBase + ks*32 + quad*8 + e];
  const unsigned short* kTb = kT + ((long)bh*NCHUNK + c)*DK*64;
  unsigned short* Wp = Wout + tokBase*DK;
  unsigned short* Up = Uout + tokBase*DK;
  #pragma unroll 1
  for (int nl=0; nl<4; nl++){
    const int d = (w*4 + nl)*16 + lo;
    f32x4 wa[4] = {}; f32x4 ua[4] = {};
    #pragma unroll
    for (int ks=0; ks<2; ks++){
      bf16x8 braw = *(const bf16x8*)&kTb[(long)d*64 + ks*32 + quad*8];
      bf16x8 bw;
      #pragma unroll
      for (int e=0; e<8; e++) bw[e] = (short)f2bf(bf2f((unsigned short)braw[e]) * b8[ks][e]);
      bf16x8 bu = *(const bf16x8*)&vT[d*72 + ks*32 + quad*8];
      #pragma unroll
      for (int mt=0; mt<4; mt++){
        bf16x8 a = *(const bf16x8*)&Pb[(mt*16+lo)*72 + ks*32 + quad*8];
        wa[mt] = MFMA(a, bw, wa[mt]);
        ua[mt] = MFMA(a, bu, ua[mt]);
      }
    }
    #pragma unroll
    for (int mt=0; mt<4; mt++)
      #pragma unroll
      for (int r=0; r<4; r++){
        int t = mt*16 + quad*4 + r;
        Wp[t*DK + d] = f2bf(wa[mt][r]);
        Up[t*DK + d] = f2bf(ua[mt][r]);
      }
  }
}

// ---------------- sequential chunk scan, v-split dv=16 per block (256 blocks) ----------------
// Round-4 verified version (201 us): 4 waves/block, W/U rolling prefetch,
// S/u fragments in regs, plain __syncthreads.
__device__ __forceinline__ int sidx(int n, int d){       // S_l [16][256] swizzled
  return n*256 + (((d>>3) ^ (n&7))<<3) + (d&7);
}
__device__ __forceinline__ int uidx(int n, int t){       // u_l [16][64] swizzled
  return n*64 + ((((t>>3) ^ (n&7)) & 7)<<3) + (t&7);
}

struct PrefWU {
  bf16x8 wf[8];          // W fragments for phase A
  unsigned short uf[4];  // U scalars for u_new epilogue
};

__device__ __forceinline__ void load_wu(PrefWU& P,
    const unsigned short* __restrict__ Wp, const unsigned short* __restrict__ Up,
    int c, int w, int lo, int quad, int vb)
{
  const unsigned short* Wc = Wp + (long)c*64*DK;
  const unsigned short* Uc = Up + (long)c*64*DK;
  #pragma unroll
  for (int ks=0; ks<8; ks++)
    P.wf[ks] = *(const bf16x8*)&Wc[(w*16+lo)*DK + ks*32 + quad*8];
  const int t0 = w*16 + quad*4;
  #pragma unroll
  for (int r=0; r<4; r++)
    P.uf[r] = Uc[(t0+r)*DK + vb*DVS + lo];
}

__device__ __forceinline__ void scan_chunk(PrefWU& P, int c, int cnext,
  const unsigned short* __restrict__ Wp, const unsigned short* __restrict__ Up,
  const unsigned short* __restrict__ qp, const unsigned short* __restrict__ kTp,
  const unsigned short* __restrict__ Ap, unsigned short* __restrict__ op,
  const unsigned short* __restrict__ Srd, unsigned short* __restrict__ Swr,
  unsigned short* __restrict__ u_l, f32x4 (&S)[4],
  int w, int lo, int quad, int vb)
{
  const unsigned short* qc = qp + (long)c*64*DK;
  const unsigned short* Ac = Ap + (long)c*64*64;
  const unsigned short* kc = kTp + (long)c*DK*64;   // chunk-tiled [256][64]
  const int t0 = w*16 + quad*4;
  // issue this chunk's q/A loads up front; consumed in phase B
  bf16x8 qf[8], af[2];
  #pragma unroll
  for (int ks=0; ks<8; ks++)
    qf[ks] = *(const bf16x8*)&qc[(w*16+lo)*DK + ks*32 + quad*8];
  #pragma unroll
  for (int ks=0; ks<2; ks++)
    af[ks] = *(const bf16x8*)&Ac[(w*16+lo)*64 + ks*32 + quad*8];

  // phase A: sb = S fragments (kept in regs for phase B); u_new = U - W*S
  bf16x8 sb[8];
  #pragma unroll
  for (int ks=0; ks<8; ks++)
    sb[ks] = *(const bf16x8*)&Srd[sidx(lo, ks*32+quad*8)];
  f32x4 ua0 = {}, ua1 = {};
  #pragma unroll
  for (int ks=0; ks<4; ks++){
    ua0 = MFMA(P.wf[ks],   sb[ks],   ua0);
    ua1 = MFMA(P.wf[ks+4], sb[ks+4], ua1);
  }
  {
    ushort4 pk;
    pk.x = f2bf(bf2f(P.uf[0]) - (ua0[0]+ua1[0]));
    pk.y = f2bf(bf2f(P.uf[1]) - (ua0[1]+ua1[1]));
    pk.z = f2bf(bf2f(P.uf[2]) - (ua0[2]+ua1[2]));
    pk.w = f2bf(bf2f(P.uf[3]) - (ua0[3]+ua1[3]));
    *(ushort4*)&u_l[uidx(lo, t0)] = pk;
  }
  __syncthreads();                                  // u_l visible

  // rolling prefetch of next chunk's W/U (P.wf dead after phase A)
  load_wu(P, Wp, Up, cnext, w, lo, quad, vb);
  // kf issue (consumed phase C, covered by phase B MFMAs)
  bf16x8 kf[4][2];
  #pragma unroll
  for (int mtl=0; mtl<4; mtl++)
    #pragma unroll
    for (int ks=0; ks<2; ks++)
      kf[mtl][ks] = *(const bf16x8*)&kc[(w*64+mtl*16+lo)*64 + ks*32 + quad*8];

  // phase B: o = q*S (reg sb) + attn*u_new
  f32x4 oa0 = {}, oa1 = {};
  #pragma unroll
  for (int ks=0; ks<4; ks++){
    oa0 = MFMA(qf[ks],   sb[ks],   oa0);
    oa1 = MFMA(qf[ks+4], sb[ks+4], oa1);
  }
  bf16x8 ub[2];
  #pragma unroll
  for (int ks=0; ks<2; ks++)
    ub[ks] = *(const bf16x8*)&u_l[uidx(lo, ks*32+quad*8)];
  #pragma unroll
  for (int ks=0; ks<2; ks++)
    oa0 = MFMA(af[ks], ub[ks], oa0);
  #pragma unroll
  for (int r=0; r<4; r++)
    op[(long)(c*64 + t0 + r)*DK + vb*DVS + lo] = f2bf(oa0[r] + oa1[r]);

  // phase C: S += k^T * u_new (ub regs reused); write S_l[other buffer]
  #pragma unroll
  for (int mtl=0; mtl<4; mtl++)
    #pragma unroll
    for (int ks=0; ks<2; ks++)
      S[mtl] = MFMA(kf[mtl][ks], ub[ks], S[mtl]);
  #pragma unroll
  for (int mtl=0; mtl<4; mtl++){
    const int d0 = w*64 + mtl*16 + quad*4;
    ushort4 pk;
    pk.x = f2bf(S[mtl][0]); pk.y = f2bf(S[mtl][1]);
    pk.z = f2bf(S[mtl][2]); pk.w = f2bf(S[mtl][3]);
    *(ushort4*)&Swr[sidx(lo, d0)] = pk;
  }
  __syncthreads();                                  // S_l[next] visible, u_l reads done
}

__global__ __launch_bounds__(256,1) void k_scan(
  const unsigned short* __restrict__ Wm, const unsigned short* __restrict__ Um,
  const unsigned short* __restrict__ qH, const unsigned short* __restrict__ kT,
  const unsigned short* __restrict__ Abuf, unsigned short* __restrict__ oH)
{
  const int bh = blockIdx.x, vb = blockIdx.y;
  __shared__ unsigned short S_l[2][DVS*256];  // bf16 mirror of state, double-buffered
  __shared__ unsigned short u_l[DVS*64];      // u_new^T [n][t]
  const int tid = threadIdx.x;
  const int w = tid >> 6, l = tid & 63, lo = l & 15, quad = l >> 4;
  for (int i = tid; i < DVS*256/4; i += 256) ((unsigned long long*)S_l[0])[i] = 0ULL;
  f32x4 S[4] = {};                            // f32 master: wave w owns d in [64w,64w+64)
  const long hb = (long)bh * LDIM;
  const unsigned short* Wp = Wm + hb*DK;
  const unsigned short* Up = Um + hb*DK;
  const unsigned short* qp = qH + hb*DK;
  const unsigned short* kTp = kT + (long)bh*NCHUNK*DK*64;
  const unsigned short* Ap = Abuf + (long)bh*NCHUNK*64*64;
  unsigned short* op = oH + hb*DK;
  PrefWU P;
  load_wu(P, Wp, Up, 0, w, lo, quad, vb);
  __syncthreads();
  #pragma unroll 1
  for (int c = 0; c < NCHUNK; c += 2){
    scan_chunk(P, c,   c+1, Wp, Up, qp, kTp, Ap, op, S_l[0], S_l[1], u_l, S, w, lo, quad, vb);
    scan_chunk(P, c+1, (c+2 < NCHUNK) ? c+2 : NCHUNK-1,
               Wp, Up, qp, kTp, Ap, op, S_l[1], S_l[0], u_l, S, w, lo, quad, vb);
  }
}

// ---------------- per-head RMSNorm * g, to [B,L,D] bf16 ----------------
__global__ __launch_bounds__(64) void k_rms(
  const unsigned short* __restrict__ oH, const float* __restrict__ g,
  unsigned short* __restrict__ oN)
{
  const int ln = blockIdx.x, bh = blockIdx.y;
  const int b = bh >> 3, h = bh & 7;
  ushort4 u = *(const ushort4*)(oH + ((long)bh*LDIM + ln)*DK + threadIdx.x*4);
  float4 v; v.x = bf2f(u.x); v.y = bf2f(u.y); v.z = bf2f(u.z); v.w = bf2f(u.w);
  float ss = v.x*v.x + v.y*v.y + v.z*v.z + v.w*v.w;
  #pragma unroll
  for (int off=32; off; off>>=1) ss += __shfl_down(ss, off, 64);
  ss = __shfl(ss, 0, 64);
  const float sc = rsqrtf(ss*(1.f/DK) + 1e-5f);
  const float4 gv = *(const float4*)(g + threadIdx.x*4);
  unsigned short* o = oN + ((long)b*LDIM + ln)*DDIM + h*DK + threadIdx.x*4;
  ushort4 pk; pk.x=f2bf(v.x*sc*gv.x); pk.y=f2bf(v.y*sc*gv.y);
  pk.z=f2bf(v.z*sc*gv.z); pk.w=f2bf(v.w*sc*gv.w);
  *(ushort4*)o = pk;
}

extern "C" void kernel_launch(void* const* d_in, const int* in_sizes, int n_in,
                              void* d_out, int out_size, void* d_ws, size_t ws_size,
                              hipStream_t stream)
{
  (void)in_sizes; (void)n_in; (void)out_size;
  const float* hs = (const float*)d_in[0];
  const float* Wq = (const float*)d_in[1];
  const float* Wk = (const float*)d_in[2];
  const float* Wv = (const float*)d_in[3];
  const float* Wb = (const float*)d_in[4];
  const float* cq = (const float*)d_in[5];
  const float* ck = (const float*)d_in[6];
  const float* cv = (const float*)d_in[7];
  const float* gn = (const float*)d_in[8];
  const float* Wo = (const float*)d_in[9];

  // Workspace plan:
  //  A 32MiB: hs_bf [cast..gemmV]          -> U    [passA..scan]
  //  B  8MiB: weight bf16 (Wq->Wk->Wv->Wo, recast sequentially)
  //  C 32MiB: pre [gemm..conv]x3 -> kT chunk-tiled [transpose..scan] -> o_norm [rms..gemmO]
  //  D 32MiB: q_head [convQ..scan]
  //  E 32MiB: k_head [convK..passA]        -> o bf16 [scan..rms]
  //  F 32MiB: v*beta [convV..passA]
  //  G  8MiB: attn tiles [passA..scan]
  //  H 256KiB: beta
  //  W 32MiB: W buffer (if ws allows; else W written in-place over F)
  const size_t SZ_TD2 = (size_t)TOK*DDIM*2;      // 32 MiB
  const size_t SZ_DD2 = (size_t)DDIM*DDIM*2;     //  8 MiB
  const size_t NEED  = 5*SZ_TD2 + 2*SZ_DD2 + (size_t)NBH*LDIM*4;
  const size_t NEEDW = NEED + SZ_TD2;
  if (ws_size < NEED){ k_guard<<<1, 64, 0, stream>>>((float*)d_out); return; }

  char* p = (char*)d_ws;
  unsigned short* bufA = (unsigned short*)p;      p += SZ_TD2;   // hs_bf / U
  unsigned short* bufB = (unsigned short*)p;      p += SZ_DD2;   // weights
  unsigned short* bufC = (unsigned short*)p;      p += SZ_TD2;   // pre / kT / o_norm
  unsigned short* bufD = (unsigned short*)p;      p += SZ_TD2;   // q_head
  unsigned short* bufE = (unsigned short*)p;      p += SZ_TD2;   // k_head / o
  unsigned short* bufF = (unsigned short*)p;      p += SZ_TD2;   // v*beta (/W fallback)
  unsigned short* bufG = (unsigned short*)p;      p += SZ_DD2;   // attn (8 MiB exactly)
  float*          beta = (float*)p;               p += (size_t)NBH*LDIM*4;
  unsigned short* bufW = (ws_size >= NEEDW) ? (unsigned short*)p : bufF;

  const dim3 gg(DDIM/256, TOK/256);   // (8, 32) = 256 blocks
  const dim3 cg(LDIM/64, NBH);
  const int nTD = TOK*DDIM, nDD = DDIM*DDIM;

  k_f2bf<<<dim3(nTD/1024), 256, 0, stream>>>(hs, bufA, nTD);
  k_beta<<<dim3(TOK), 256, 0, stream>>>(hs, Wb, beta);

  k_f2bf<<<dim3(nDD/1024), 256, 0, stream>>>(Wq, bufB, nDD);
  k_gemm256<false><<<gg, 512, 0, stream>>>(bufA, bufB, bufC, TOK, DDIM, DDIM);
  k_conv<<<cg, 256, 0, stream>>>(bufC, cq, beta, bufD, 0);

  k_f2bf<<<dim3(nDD/1024), 256, 0, stream>>>(Wk, bufB, nDD);
  k_gemm256<false><<<gg, 512, 0, stream>>>(bufA, bufB, bufC, TOK, DDIM, DDIM);
  k_conv<<<cg, 256, 0, stream>>>(bufC, ck, beta, bufE, 1);

  k_f2bf<<<dim3(nDD/1024), 256, 0, stream>>>(Wv, bufB, nDD);
  k_gemm256<false><<<gg, 512, 0, stream>>>(bufA, bufB, bufC, TOK, DDIM, DDIM);
  k_conv<<<cg, 256, 0, stream>>>(bufC, cv, beta, bufF, 2);

  k_transpose<<<dim3(LDIM/64, DK/64, NBH), 256, 0, stream>>>(bufE, bufC);      // kT -> C
  k_passA<<<dim3(NCHUNK, NBH), 256, 0, stream>>>(bufD, bufE, bufF, bufC, beta,
                                                 bufW, bufA /*U*/, bufG);
  k_scan<<<dim3(NBH, 16), 256, 0, stream>>>(bufW, bufA, bufD, bufC, bufG, bufE); // o -> E
  k_rms<<<dim3(LDIM, NBH), 64, 0, stream>>>(bufE, gn, bufC);                     // o_norm -> C

  k_f2bf<<<dim3(nDD/1024), 256, 0, stream>>>(Wo, bufB, nDD);
  k_gemm256<true><<<gg, 512, 0, stream>>>(bufC, bufB, d_out /*f32*/, TOK, DDIM, DDIM);
}

// Round 7
// 864.430 us; speedup vs baseline: 2.0264x; 1.0046x over previous
//
#include <hip/hip_runtime.h>
#include <stdint.h>

#define TOK    8192   // B*L
#define LDIM   4096
#define DDIM   2048
#define NBH    16     // B*H
#define DK     256
#define NCHUNK 64
#define DVS    16     // v-slice width per scan block

typedef __attribute__((ext_vector_type(8))) short bf16x8;   // 8 bf16 (4 VGPRs)
typedef __attribute__((ext_vector_type(4))) float f32x4;

#define MFMA(a,b,c) __builtin_amdgcn_mfma_f32_16x16x32_bf16((a),(b),(c),0,0,0)

__device__ __forceinline__ unsigned short f2bf(float f){
  union { float f; uint32_t u; } v; v.f = f;
  uint32_t r = v.u + 0x7FFFu + ((v.u >> 16) & 1u);   // RNE
  return (unsigned short)(r >> 16);
}
__device__ __forceinline__ float bf2f(unsigned short u){
  union { uint32_t u; float f; } v; v.u = ((uint32_t)u) << 16;
  return v.f;
}

typedef __attribute__((address_space(1))) unsigned int as1_u32;
typedef __attribute__((address_space(3))) unsigned int as3_u32;
__device__ __forceinline__ void gload16(const void* g, void* l){
  __builtin_amdgcn_global_load_lds((const as1_u32*)g, (as3_u32*)l, 16, 0, 0);
}

// LDS-only barrier: waits all my DS ops (lgkmcnt) then barriers, WITHOUT draining
// vmcnt — global_load_lds prefetches stay in flight across it (T3/T4 mechanism).
__device__ __forceinline__ void bar_lds(){
  asm volatile("s_waitcnt lgkmcnt(0)\n\ts_barrier" ::: "memory");
}

// ---------------- guard (ws too small): clean fail, non-empty graph ----------------
__global__ void k_guard(float* o){ if (threadIdx.x == 0) o[0] = 0.f; }

// ---------------- f32 -> bf16 cast ----------------
__global__ __launch_bounds__(256) void k_f2bf(const float* __restrict__ s,
                                              unsigned short* __restrict__ d, int n)
{
  int i = (blockIdx.x*256 + threadIdx.x)*4;
  if (i >= n) return;
  float4 v = *(const float4*)(s + i);
  ushort4 o; o.x=f2bf(v.x); o.y=f2bf(v.y); o.z=f2bf(v.z); o.w=f2bf(v.w);
  *(ushort4*)(d + i) = o;
}

// ---------------- beta = sigmoid(hs @ Wb^T), [bh][l]; ALSO writes hs_bf ----------------
// Fusion: this kernel already streams all of hs in f32; emitting the bf16 cast
// here removes the separate 96MB-traffic k_f2bf pass over hs.
__global__ __launch_bounds__(256) void k_beta(const float* __restrict__ hs,
                                              const float* __restrict__ Wb,
                                              float* __restrict__ beta,
                                              unsigned short* __restrict__ hsb)
{
  const long t = blockIdx.x;          // token
  const int tid = threadIdx.x;
  float acc[8] = {0,0,0,0,0,0,0,0};
  const float* xr = hs + t*DDIM;
  unsigned short* hb = hsb + t*DDIM;
  for (int i = tid; i < DDIM; i += 256){
    float x = xr[i];
    hb[i] = f2bf(x);
    #pragma unroll
    for (int h=0; h<8; h++) acc[h] += x * Wb[h*DDIM + i];
  }
  __shared__ float red[8][4];
  const int w = tid >> 6, lane = tid & 63;
  #pragma unroll
  for (int h=0; h<8; h++){
    float s = acc[h];
    #pragma unroll
    for (int off=32; off; off>>=1) s += __shfl_down(s, off, 64);
    if (lane == 0) red[h][w] = s;
  }
  __syncthreads();
  if (tid < 8){
    float s = red[tid][0]+red[tid][1]+red[tid][2]+red[tid][3];
    float bv = 1.f/(1.f + __expf(-s));
    int b = (int)(t >> 12), l = (int)(t & 4095);
    beta[((long)(b*8 + tid))*LDIM + l] = bv;
  }
}

// ---------------- GEMM 256x256 tile, BK=32, 4-deep LDS ring, counted vmcnt ----------------
// C[M,N] = A[M,K] * B[N,K]^T, bf16 in, bf16 or f32 out.
// T2: bank-swizzle, both-sides (rule #21): linear gload_lds dest + inverse-XOR'd
//     GLOBAL source col + same XOR on ds_read.
//     swz(row) = (((row>>1)&3)<<4) bytes. Bank census for a quad's 16 lanes
//     (rows base..base+15): (parity=row&1) x (slot=(row>>1)&3) = 8 distinct
//     4-bank groups, 2 lanes each = conflict-FREE (m136: 2-way = 1.02x).
//     [Round-6 used (row&3)<<4: parity and slot correlated -> lanes lo,lo+4,
//      lo+8,lo+12 collided = 4-way = 1.58x LDS cost. LDS reads are this
//      blocking's dominant resource (96KB/K-tile/CU) -> the main fix.]
// T3/T4: stage tile t+2 while computing tile t; vmcnt(8) steady state (never 0);
//        one lgkm-only barrier per K-tile. Ring distance 2 => no buffer collision.
template <bool F32OUT>
__global__ __launch_bounds__(512) void k_gemm256(
    const unsigned short* __restrict__ A, const unsigned short* __restrict__ Bw,
    void* __restrict__ Cv, int M, int N, int K)
{
  __shared__ unsigned short As[4][256*32];   // 4 x 16 KiB
  __shared__ unsigned short Bs[4][256*32];   // 4 x 16 KiB  (128 KiB total)
  const int tid = threadIdx.x;
  const int w = tid >> 6, l = tid & 63;
  const int lo = l & 15, quad = l >> 4;
  const int wm = w >> 2, wn = w & 3;         // 2 x 4 waves, per-wave 128x64 out
  // T1: XCD-aware bijective block swizzle (nwg % 8 == 0 here)
  const int gx = gridDim.x;
  int id = blockIdx.y * gx + blockIdx.x;
  const int nwg = gx * gridDim.y;
  if ((nwg & 7) == 0){ const int q8 = nwg >> 3; id = (id & 7)*q8 + (id >> 3); }
  const int bx = id % gx, by = id / gx;
  const long tm = (long)by * 256, tn = (long)bx * 256;

  // staging: 1024 slots of 16B per matrix per tile; thread -> slots (w*2+j)*64+l
  // LDS linear byte = slot*16; row = slot>>2; colB = (slot&3)*16;
  // global source col-bytes = colB ^ swz(row), swz(row)=(((row>>1)&3)<<4)
  const int slot0 = (w*2+0)*64 + l;
  const int slot1 = (w*2+1)*64 + l;
  const int r0 = slot0 >> 2, c0 = ((slot0 & 3)*16) ^ (((r0 >> 1) & 3) << 4);
  const int r1 = slot1 >> 2, c1 = ((slot1 & 3)*16) ^ (((r1 >> 1) & 3) << 4);
  const unsigned short* pA0 = A  + (tm + r0)*(long)K + (c0 >> 1);
  const unsigned short* pA1 = A  + (tm + r1)*(long)K + (c1 >> 1);
  const unsigned short* pB0 = Bw + (tn + r0)*(long)K + (c0 >> 1);
  const unsigned short* pB1 = Bw + (tn + r1)*(long)K + (c1 >> 1);
  // ds_read swizzled col offset (shorts): quad*16B ^ swz(row); row&15 == lo
  const int asw = ((quad*16) ^ (((lo >> 1) & 3) << 4)) >> 1;

  f32x4 acc[8][4] = {};
  const int nt = K >> 5;                     // K-tiles of 32 (nt >= 3)

#define STAGE(t_) do { const int kk_ = (t_)*32, b_ = (t_) & 3;      \
    gload16(pA0 + kk_, &As[b_][slot0*8]);                           \
    gload16(pA1 + kk_, &As[b_][slot1*8]);                           \
    gload16(pB0 + kk_, &Bs[b_][slot0*8]);                           \
    gload16(pB1 + kk_, &Bs[b_][slot1*8]); } while(0)

#define COMPUTE(t_) do { const int b_ = (t_) & 3;                              \
    bf16x8 af[8], bg[4];                                                       \
    _Pragma("unroll")                                                          \
    for (int mf=0; mf<8; mf++)                                                 \
      af[mf] = *(const bf16x8*)&As[b_][(wm*128 + mf*16 + lo)*32 + asw];        \
    _Pragma("unroll")                                                          \
    for (int nf=0; nf<4; nf++)                                                 \
      bg[nf] = *(const bf16x8*)&Bs[b_][(wn*64 + nf*16 + lo)*32 + asw];         \
    _Pragma("unroll")                                                          \
    for (int mf=0; mf<8; mf++)                                                 \
      _Pragma("unroll")                                                        \
      for (int nf=0; nf<4; nf++)                                               \
        acc[mf][nf] = MFMA(af[mf], bg[nf], acc[mf][nf]); } while(0)

  STAGE(0); STAGE(1);
  #pragma unroll 1
  for (int t = 0; t < nt-2; ++t){
    STAGE(t+2);                                        // 2 tiles ahead
    asm volatile("s_waitcnt vmcnt(8)" ::: "memory");   // wait tile t only
    bar_lds();
    COMPUTE(t);
  }
  asm volatile("s_waitcnt vmcnt(4)" ::: "memory");
  bar_lds();
  COMPUTE(nt-2);
  asm volatile("s_waitcnt vmcnt(0)" ::: "memory");
  bar_lds();
  COMPUTE(nt-1);
#undef STAGE
#undef COMPUTE

  #pragma unroll
  for (int mf=0; mf<8; mf++)
    #pragma unroll
    for (int nf=0; nf<4; nf++)
      #pragma unroll
      for (int r=0; r<4; r++){
        long m = tm + wm*128 + mf*16 + quad*4 + r;
        long n = tn + wn*64 + nf*16 + lo;
        if (F32OUT) ((float*)Cv)[m*N + n] = acc[mf][nf][r];
        else ((unsigned short*)Cv)[m*N + n] = f2bf(acc[mf][nf][r]);
      }
}

// ---------------- causal conv(K=4)+silu (+l2norm q/k, *beta for v), head layout out ----------------
// mode: 0=q (l2norm + dk^-0.5), 1=k (l2norm), 2=v (silu * beta)
__global__ __launch_bounds__(256) void k_conv(
  const unsigned short* __restrict__ X, const float* __restrict__ Wc,
  const float* __restrict__ beta,
  unsigned short* __restrict__ O, int mode)
{
  const int lt = blockIdx.x, bh = blockIdx.y;
  const int b = bh >> 3, h = bh & 7;
  const int d = threadIdx.x;                 // 0..255 within head
  const int ch = h*256 + d;
  const int l0 = lt*64;
  const unsigned short* xp = X + (long)b*LDIM*DDIM + ch;
  const float4 wv = *(const float4*)(Wc + ch*4);
  float x0=0.f, x1=0.f, x2=0.f;
  if (l0 >= 3){
    x0 = bf2f(xp[(long)(l0-3)*DDIM]);
    x1 = bf2f(xp[(long)(l0-2)*DDIM]);
    x2 = bf2f(xp[(long)(l0-1)*DDIM]);
  }
  float y[64];
  #pragma unroll
  for (int i=0;i<64;i++){
    float x3 = bf2f(xp[(long)(l0+i)*DDIM]);
    float s = x0*wv.x + x1*wv.y + x2*wv.z + x3*wv.w;
    y[i] = s / (1.f + __expf(-s));
    x0 = x1; x1 = x2; x2 = x3;
  }
  unsigned short* op = O + (long)bh*LDIM*DK + d;
  if (mode == 2){
    const float* bet = beta + (long)bh*LDIM + l0;
    #pragma unroll
    for (int i=0;i<64;i++) op[(long)(l0+i)*DK] = f2bf(y[i]*bet[i]);
    return;
  }
  __shared__ float red[64*4];
  __shared__ float scl[64];
  const int wv_i = threadIdx.x >> 6, lane = threadIdx.x & 63;
  #pragma unroll
  for (int i=0;i<64;i++){
    float ss = y[i]*y[i];
    #pragma unroll
    for (int off=32; off; off>>=1) ss += __shfl_down(ss, off, 64);
    if (lane == 0) red[i*4 + wv_i] = ss;
  }
  __syncthreads();
  if (threadIdx.x < 64){
    int i = threadIdx.x;
    float s = red[i*4]+red[i*4+1]+red[i*4+2]+red[i*4+3];
    scl[i] = rsqrtf(s + 1e-6f) * (mode==0 ? 0.0625f : 1.f);   // dk^-0.5 folded into q
  }
  __syncthreads();
  #pragma unroll
  for (int i=0;i<64;i++) op[(long)(l0+i)*DK] = f2bf(y[i]*scl[i]);
}

// ---------------- transpose k: CHUNK-TILED kT[bh][c][d][64] (rows 128B) ----------------
__global__ __launch_bounds__(256) void k_transpose(
  const unsigned short* __restrict__ kH, unsigned short* __restrict__ kT)
{
  const int lt = blockIdx.x, dt = blockIdx.y, bh = blockIdx.z;
  __shared__ unsigned short tk[64][72];   // 144B rows, 16B aligned
  const int tid = threadIdx.x;
  const int rl = tid >> 2, c0 = (tid & 3) * 16;
  const long base = ((long)bh*LDIM + lt*64 + rl)*DK + dt*64 + c0;
  *(bf16x8*)&tk[rl][c0]   = *(const bf16x8*)(kH + base);
  *(bf16x8*)&tk[rl][c0+8] = *(const bf16x8*)(kH + base + 8);
  __syncthreads();
  const int rd = tid >> 2, lc0 = (tid & 3) * 16;
  bf16x8 ok0, ok1;
  #pragma unroll
  for (int j=0;j<16;j++){
    unsigned short kraw = tk[lc0+j][rd];
    if (j < 8) ok0[j] = (short)kraw; else ok1[j-8] = (short)kraw;
  }
  const long ob = (((long)bh*NCHUNK + lt)*DK + dt*64 + rd)*64 + lc0;
  *(bf16x8*)(kT + ob) = ok0; *(bf16x8*)(kT + ob + 8) = ok1;
}

// ---------------- pass A: per (bh,chunk) attn, T=(I+M)^-1 (Neumann product), W=T*Kb, U=T*Vb ----------------
__global__ __launch_bounds__(256) void k_passA(
  const unsigned short* __restrict__ qH, const unsigned short* __restrict__ kH,
  const unsigned short* vbH,            // v*beta [bh][l][dk] (may alias Wout in fallback)
  const unsigned short* __restrict__ kT,
  const float* __restrict__ beta,
  unsigned short* Wout,
  unsigned short* __restrict__ Uout,
  unsigned short* __restrict__ Aout)
{
  const int c = blockIdx.x, bh = blockIdx.y;
  __shared__ unsigned short Nn[64*72];
  __shared__ unsigned short NT[64*72];
  __shared__ unsigned short Pb[64*72];
  __shared__ unsigned short vT[256*72];   // vb^T [d][s], stride 72 (63KiB total)
  const int tid = threadIdx.x;
  const int w = tid >> 6, l = tid & 63, lo = l & 15, quad = l >> 4;
  const long tokBase = (long)bh*LDIM + c*64;
  const unsigned short* qrow = qH + tokBase*DK;
  const unsigned short* krow = kH + tokBase*DK;
  const float bv = beta[tokBase + w*16 + lo];

  // stage vT = vb^T (all vbH reads complete before first barrier)
  {
    const int r = tid >> 2, cs = (tid & 3) * 64;
    const unsigned short* vrow = vbH + (tokBase + r)*DK + cs;
    bf16x8 vv[8];
    #pragma unroll
    for (int j=0;j<8;j++) vv[j] = *(const bf16x8*)(vrow + j*8);
    #pragma unroll
    for (int j=0;j<8;j++)
      #pragma unroll
      for (int e=0;e<8;e++)
        vT[(cs + j*8 + e)*72 + r] = (unsigned short)vv[j][e];
  }

  // M = Kb K^T (strict lower), attn = tril(Q K^T)
  f32x4 mAcc[4] = {}; f32x4 aAcc[4] = {};
  #pragma unroll
  for (int ks=0; ks<8; ks++){
    bf16x8 kf[4];
    #pragma unroll
    for (int nt=0; nt<4; nt++)
      kf[nt] = *(const bf16x8*)&krow[(nt*16+lo)*DK + ks*32 + quad*8];
    bf16x8 qf  = *(const bf16x8*)&qrow[(w*16+lo)*DK + ks*32 + quad*8];
    bf16x8 kfw = *(const bf16x8*)&krow[(w*16+lo)*DK + ks*32 + quad*8];
    bf16x8 kbf;
    #pragma unroll
    for (int j=0;j<8;j++) kbf[j] = (short)f2bf(bf2f((unsigned short)kfw[j]) * bv);
    #pragma unroll
    for (int nt=0; nt<4; nt++){
      mAcc[nt] = MFMA(kbf, kf[nt], mAcc[nt]);
      aAcc[nt] = MFMA(qf,  kf[nt], aAcc[nt]);
    }
  }
  unsigned short* Ap = Aout + ((long)bh*NCHUNK + c)*64*64;
  #pragma unroll
  for (int nt=0; nt<4; nt++)
    #pragma unroll
    for (int r=0; r<4; r++){
      int t = w*16 + quad*4 + r, s = nt*16 + lo;
      float mv = (t > s) ? mAcc[nt][r] : 0.f;
      unsigned short mb = f2bf(mv);
      Nn[t*72+s] = mb;
      NT[s*72+t] = mb;
      Pb[t*72+s] = f2bf((t==s ? 1.f : 0.f) - mv);
      Ap[t*64+s] = f2bf((t >= s) ? aAcc[nt][r] : 0.f);
    }
  __syncthreads();

  // (I+N)^-1 = (I-N)(I+N^2)(I+N^4)(I+N^8)(I+N^16)(I+N^32); single-buffered w/ reg prefetch
  #pragma unroll 1
  for (int it=0; it<5; it++){
    bf16x8 aN[2], aP[2], bN[2][4];
    #pragma unroll
    for (int ks=0; ks<2; ks++){
      aN[ks] = *(const bf16x8*)&Nn[(w*16+lo)*72 + ks*32 + quad*8];
      aP[ks] = *(const bf16x8*)&Pb[(w*16+lo)*72 + ks*32 + quad*8];
      #pragma unroll
      for (int nt=0; nt<4; nt++)
        bN[ks][nt] = *(const bf16x8*)&NT[(nt*16+lo)*72 + ks*32 + quad*8];
    }
    f32x4 pp[4];
    #pragma unroll
    for (int nt=0; nt<4; nt++)
      #pragma unroll
      for (int r=0; r<4; r++)
        pp[nt][r] = bf2f(Pb[(w*16+quad*4+r)*72 + nt*16+lo]);
    __syncthreads();                     // all reads of cur done
    f32x4 sq[4] = {};
    #pragma unroll
    for (int ks=0; ks<2; ks++)
      #pragma unroll
      for (int nt=0; nt<4; nt++)
        sq[nt] = MFMA(aN[ks], bN[ks][nt], sq[nt]);
    #pragma unroll
    for (int nt=0; nt<4; nt++)
      #pragma unroll
      for (int r=0; r<4; r++){
        int t = w*16 + quad*4 + r, s = nt*16 + lo;
        unsigned short vb2 = f2bf(sq[nt][r]);
        Nn[t*72+s] = vb2; NT[s*72+t] = vb2;
      }
    __syncthreads();                     // N^2 visible
    #pragma unroll
    for (int ks=0; ks<2; ks++)
      #pragma unroll
      for (int nt=0; nt<4; nt++){
        bf16x8 b = *(const bf16x8*)&NT[(nt*16+lo)*72 + ks*32 + quad*8];
        pp[nt] = MFMA(aP[ks], b, pp[nt]);
      }
    #pragma unroll
    for (int nt=0; nt<4; nt++)
      #pragma unroll
      for (int r=0; r<4; r++)
        Pb[(w*16+quad*4+r)*72 + nt*16+lo] = f2bf(pp[nt][r]);
    __syncthreads();                     // P_next visible
  }

  // W = T*Kb (B from chunk-tiled kT rows, beta-scaled inline), U = T*Vb (B from vT LDS)
  float b8[2][8];
  #pragma unroll
  for (int ks=0; ks<2; ks++)
    #pragma unroll
    for (int e=0; e<8; e++)
      b8[ks][e] = beta[tokBase + ks*32 + quad*8 + e];
  const unsigned short* kTb = kT + ((long)bh*NCHUNK + c)*DK*64;
  unsigned short* Wp = Wout + tokBase*DK;
  unsigned short* Up = Uout + tokBase*DK;
  #pragma unroll 1
  for (int nl=0; nl<4; nl++){
    const int d = (w*4 + nl)*16 + lo;
    f32x4 wa[4] = {}; f32x4 ua[4] = {};
    #pragma unroll
    for (int ks=0; ks<2; ks++){
      bf16x8 braw = *(const bf16x8*)&kTb[(long)d*64 + ks*32 + quad*8];
      bf16x8 bw;
      #pragma unroll
      for (int e=0; e<8; e++) bw[e] = (short)f2bf(bf2f((unsigned short)braw[e]) * b8[ks][e]);
      bf16x8 bu = *(const bf16x8*)&vT[d*72 + ks*32 + quad*8];
      #pragma unroll
      for (int mt=0; mt<4; mt++){
        bf16x8 a = *(const bf16x8*)&Pb[(mt*16+lo)*72 + ks*32 + quad*8];
        wa[mt] = MFMA(a, bw, wa[mt]);
        ua[mt] = MFMA(a, bu, ua[mt]);
      }
    }
    #pragma unroll
    for (int mt=0; mt<4; mt++)
      #pragma unroll
      for (int r=0; r<4; r++){
        int t = mt*16 + quad*4 + r;
        Wp[t*DK + d] = f2bf(wa[mt][r]);
        Up[t*DK + d] = f2bf(ua[mt][r]);
      }
  }
}

// ---------------- sequential chunk scan, v-split dv=16 per block (256 blocks) ----------------
// Round-4 verified version (201 us): 4 waves/block, W/U rolling prefetch,
// S/u fragments in regs, plain __syncthreads.
__device__ __forceinline__ int sidx(int n, int d){       // S_l [16][256] swizzled
  return n*256 + (((d>>3) ^ (n&7))<<3) + (d&7);
}
__device__ __forceinline__ int uidx(int n, int t){       // u_l [16][64] swizzled
  return n*64 + ((((t>>3) ^ (n&7)) & 7)<<3) + (t&7);
}

struct PrefWU {
  bf16x8 wf[8];          // W fragments for phase A
  unsigned short uf[4];  // U scalars for u_new epilogue
};

__device__ __forceinline__ void load_wu(PrefWU& P,
    const unsigned short* __restrict__ Wp, const unsigned short* __restrict__ Up,
    int c, int w, int lo, int quad, int vb)
{
  const unsigned short* Wc = Wp + (long)c*64*DK;
  const unsigned short* Uc = Up + (long)c*64*DK;
  #pragma unroll
  for (int ks=0; ks<8; ks++)
    P.wf[ks] = *(const bf16x8*)&Wc[(w*16+lo)*DK + ks*32 + quad*8];
  const int t0 = w*16 + quad*4;
  #pragma unroll
  for (int r=0; r<4; r++)
    P.uf[r] = Uc[(t0+r)*DK + vb*DVS + lo];
}

__device__ __forceinline__ void scan_chunk(PrefWU& P, int c, int cnext,
  const unsigned short* __restrict__ Wp, const unsigned short* __restrict__ Up,
  const unsigned short* __restrict__ qp, const unsigned short* __restrict__ kTp,
  const unsigned short* __restrict__ Ap, unsigned short* __restrict__ op,
  const unsigned short* __restrict__ Srd, unsigned short* __restrict__ Swr,
  unsigned short* __restrict__ u_l, f32x4 (&S)[4],
  int w, int lo, int quad, int vb)
{
  const unsigned short* qc = qp + (long)c*64*DK;
  const unsigned short* Ac = Ap + (long)c*64*64;
  const unsigned short* kc = kTp + (long)c*DK*64;   // chunk-tiled [256][64]
  const int t0 = w*16 + quad*4;
  // issue this chunk's q/A loads up front; consumed in phase B
  bf16x8 qf[8], af[2];
  #pragma unroll
  for (int ks=0; ks<8; ks++)
    qf[ks] = *(const bf16x8*)&qc[(w*16+lo)*DK + ks*32 + quad*8];
  #pragma unroll
  for (int ks=0; ks<2; ks++)
    af[ks] = *(const bf16x8*)&Ac[(w*16+lo)*64 + ks*32 + quad*8];

  // phase A: sb = S fragments (kept in regs for phase B); u_new = U - W*S
  bf16x8 sb[8];
  #pragma unroll
  for (int ks=0; ks<8; ks++)
    sb[ks] = *(const bf16x8*)&Srd[sidx(lo, ks*32+quad*8)];
  f32x4 ua0 = {}, ua1 = {};
  #pragma unroll
  for (int ks=0; ks<4; ks++){
    ua0 = MFMA(P.wf[ks],   sb[ks],   ua0);
    ua1 = MFMA(P.wf[ks+4], sb[ks+4], ua1);
  }
  {
    ushort4 pk;
    pk.x = f2bf(bf2f(P.uf[0]) - (ua0[0]+ua1[0]));
    pk.y = f2bf(bf2f(P.uf[1]) - (ua0[1]+ua1[1]));
    pk.z = f2bf(bf2f(P.uf[2]) - (ua0[2]+ua1[2]));
    pk.w = f2bf(bf2f(P.uf[3]) - (ua0[3]+ua1[3]));
    *(ushort4*)&u_l[uidx(lo, t0)] = pk;
  }
  __syncthreads();                                  // u_l visible

  // rolling prefetch of next chunk's W/U (P.wf dead after phase A)
  load_wu(P, Wp, Up, cnext, w, lo, quad, vb);
  // kf issue (consumed phase C, covered by phase B MFMAs)
  bf16x8 kf[4][2];
  #pragma unroll
  for (int mtl=0; mtl<4; mtl++)
    #pragma unroll
    for (int ks=0; ks<2; ks++)
      kf[mtl][ks] = *(const bf16x8*)&kc[(w*64+mtl*16+lo)*64 + ks*32 + quad*8];

  // phase B: o = q*S (reg sb) + attn*u_new
  f32x4 oa0 = {}, oa1 = {};
  #pragma unroll
  for (int ks=0; ks<4; ks++){
    oa0 = MFMA(qf[ks],   sb[ks],   oa0);
    oa1 = MFMA(qf[ks+4], sb[ks+4], oa1);
  }
  bf16x8 ub[2];
  #pragma unroll
  for (int ks=0; ks<2; ks++)
    ub[ks] = *(const bf16x8*)&u_l[uidx(lo, ks*32+quad*8)];
  #pragma unroll
  for (int ks=0; ks<2; ks++)
    oa0 = MFMA(af[ks], ub[ks], oa0);
  #pragma unroll
  for (int r=0; r<4; r++)
    op[(long)(c*64 + t0 + r)*DK + vb*DVS + lo] = f2bf(oa0[r] + oa1[r]);

  // phase C: S += k^T * u_new (ub regs reused); write S_l[other buffer]
  #pragma unroll
  for (int mtl=0; mtl<4; mtl++)
    #pragma unroll
    for (int ks=0; ks<2; ks++)
      S[mtl] = MFMA(kf[mtl][ks], ub[ks], S[mtl]);
  #pragma unroll
  for (int mtl=0; mtl<4; mtl++){
    const int d0 = w*64 + mtl*16 + quad*4;
    ushort4 pk;
    pk.x = f2bf(S[mtl][0]); pk.y = f2bf(S[mtl][1]);
    pk.z = f2bf(S[mtl][2]); pk.w = f2bf(S[mtl][3]);
    *(ushort4*)&Swr[sidx(lo, d0)] = pk;
  }
  __syncthreads();                                  // S_l[next] visible, u_l reads done
}

__global__ __launch_bounds__(256,1) void k_scan(
  const unsigned short* __restrict__ Wm, const unsigned short* __restrict__ Um,
  const unsigned short* __restrict__ qH, const unsigned short* __restrict__ kT,
  const unsigned short* __restrict__ Abuf, unsigned short* __restrict__ oH)
{
  const int bh = blockIdx.x, vb = blockIdx.y;
  __shared__ unsigned short S_l[2][DVS*256];  // bf16 mirror of state, double-buffered
  __shared__ unsigned short u_l[DVS*64];      // u_new^T [n][t]
  const int tid = threadIdx.x;
  const int w = tid >> 6, l = tid & 63, lo = l & 15, quad = l >> 4;
  for (int i = tid; i < DVS*256/4; i += 256) ((unsigned long long*)S_l[0])[i] = 0ULL;
  f32x4 S[4] = {};                            // f32 master: wave w owns d in [64w,64w+64)
  const long hb = (long)bh * LDIM;
  const unsigned short* Wp = Wm + hb*DK;
  const unsigned short* Up = Um + hb*DK;
  const unsigned short* qp = qH + hb*DK;
  const unsigned short* kTp = kT + (long)bh*NCHUNK*DK*64;
  const unsigned short* Ap = Abuf + (long)bh*NCHUNK*64*64;
  unsigned short* op = oH + hb*DK;
  PrefWU P;
  load_wu(P, Wp, Up, 0, w, lo, quad, vb);
  __syncthreads();
  #pragma unroll 1
  for (int c = 0; c < NCHUNK; c += 2){
    scan_chunk(P, c,   c+1, Wp, Up, qp, kTp, Ap, op, S_l[0], S_l[1], u_l, S, w, lo, quad, vb);
    scan_chunk(P, c+1, (c+2 < NCHUNK) ? c+2 : NCHUNK-1,
               Wp, Up, qp, kTp, Ap, op, S_l[1], S_l[0], u_l, S, w, lo, quad, vb);
  }
}

// ---------------- per-head RMSNorm * g, to [B,L,D] bf16 ----------------
__global__ __launch_bounds__(64) void k_rms(
  const unsigned short* __restrict__ oH, const float* __restrict__ g,
  unsigned short* __restrict__ oN)
{
  const int ln = blockIdx.x, bh = blockIdx.y;
  const int b = bh >> 3, h = bh & 7;
  ushort4 u = *(const ushort4*)(oH + ((long)bh*LDIM + ln)*DK + threadIdx.x*4);
  float4 v; v.x = bf2f(u.x); v.y = bf2f(u.y); v.z = bf2f(u.z); v.w = bf2f(u.w);
  float ss = v.x*v.x + v.y*v.y + v.z*v.z + v.w*v.w;
  #pragma unroll
  for (int off=32; off; off>>=1) ss += __shfl_down(ss, off, 64);
  ss = __shfl(ss, 0, 64);
  const float sc = rsqrtf(ss*(1.f/DK) + 1e-5f);
  const float4 gv = *(const float4*)(g + threadIdx.x*4);
  unsigned short* o = oN + ((long)b*LDIM + ln)*DDIM + h*DK + threadIdx.x*4;
  ushort4 pk; pk.x=f2bf(v.x*sc*gv.x); pk.y=f2bf(v.y*sc*gv.y);
  pk.z=f2bf(v.z*sc*gv.z); pk.w=f2bf(v.w*sc*gv.w);
  *(ushort4*)o = pk;
}

extern "C" void kernel_launch(void* const* d_in, const int* in_sizes, int n_in,
                              void* d_out, int out_size, void* d_ws, size_t ws_size,
                              hipStream_t stream)
{
  (void)in_sizes; (void)n_in; (void)out_size;
  const float* hs = (const float*)d_in[0];
  const float* Wq = (const float*)d_in[1];
  const float* Wk = (const float*)d_in[2];
  const float* Wv = (const float*)d_in[3];
  const float* Wb = (const float*)d_in[4];
  const float* cq = (const float*)d_in[5];
  const float* ck = (const float*)d_in[6];
  const float* cv = (const float*)d_in[7];
  const float* gn = (const float*)d_in[8];
  const float* Wo = (const float*)d_in[9];

  // Workspace plan:
  //  A 32MiB: hs_bf [beta..gemmV]          -> U    [passA..scan]
  //  B  8MiB: weight bf16 (Wq->Wk->Wv->Wo, recast sequentially)
  //  C 32MiB: pre [gemm..conv]x3 -> kT chunk-tiled [transpose..scan] -> o_norm [rms..gemmO]
  //  D 32MiB: q_head [convQ..scan]
  //  E 32MiB: k_head [convK..passA]        -> o bf16 [scan..rms]
  //  F 32MiB: v*beta [convV..passA]
  //  G  8MiB: attn tiles [passA..scan]
  //  H 256KiB: beta
  //  W 32MiB: W buffer (if ws allows; else W written in-place over F)
  const size_t SZ_TD2 = (size_t)TOK*DDIM*2;      // 32 MiB
  const size_t SZ_DD2 = (size_t)DDIM*DDIM*2;     //  8 MiB
  const size_t NEED  = 5*SZ_TD2 + 2*SZ_DD2 + (size_t)NBH*LDIM*4;
  const size_t NEEDW = NEED + SZ_TD2;
  if (ws_size < NEED){ k_guard<<<1, 64, 0, stream>>>((float*)d_out); return; }

  char* p = (char*)d_ws;
  unsigned short* bufA = (unsigned short*)p;      p += SZ_TD2;   // hs_bf / U
  unsigned short* bufB = (unsigned short*)p;      p += SZ_DD2;   // weights
  unsigned short* bufC = (unsigned short*)p;      p += SZ_TD2;   // pre / kT / o_norm
  unsigned short* bufD = (unsigned short*)p;      p += SZ_TD2;   // q_head
  unsigned short* bufE = (unsigned short*)p;      p += SZ_TD2;   // k_head / o
  unsigned short* bufF = (unsigned short*)p;      p += SZ_TD2;   // v*beta (/W fallback)
  unsigned short* bufG = (unsigned short*)p;      p += SZ_DD2;   // attn (8 MiB exactly)
  float*          beta = (float*)p;               p += (size_t)NBH*LDIM*4;
  unsigned short* bufW = (ws_size >= NEEDW) ? (unsigned short*)p : bufF;

  const dim3 gg(DDIM/256, TOK/256);   // (8, 32) = 256 blocks
  const dim3 cg(LDIM/64, NBH);
  const int nDD = DDIM*DDIM;

  k_beta<<<dim3(TOK), 256, 0, stream>>>(hs, Wb, beta, bufA);   // beta + hs->bf16 fused

  k_f2bf<<<dim3(nDD/1024), 256, 0, stream>>>(Wq, bufB, nDD);
  k_gemm256<false><<<gg, 512, 0, stream>>>(bufA, bufB, bufC, TOK, DDIM, DDIM);
  k_conv<<<cg, 256, 0, stream>>>(bufC, cq, beta, bufD, 0);

  k_f2bf<<<dim3(nDD/1024), 256, 0, stream>>>(Wk, bufB, nDD);
  k_gemm256<false><<<gg, 512, 0, stream>>>(bufA, bufB, bufC, TOK, DDIM, DDIM);
  k_conv<<<cg, 256, 0, stream>>>(bufC, ck, beta, bufE, 1);

  k_f2bf<<<dim3(nDD/1024), 256, 0, stream>>>(Wv, bufB, nDD);
  k_gemm256<false><<<gg, 512, 0, stream>>>(bufA, bufB, bufC, TOK, DDIM, DDIM);
  k_conv<<<cg, 256, 0, stream>>>(bufC, cv, beta, bufF, 2);

  k_transpose<<<dim3(LDIM/64, DK/64, NBH), 256, 0, stream>>>(bufE, bufC);      // kT -> C
  k_passA<<<dim3(NCHUNK, NBH), 256, 0, stream>>>(bufD, bufE, bufF, bufC, beta,
                                                 bufW, bufA /*U*/, bufG);
  k_scan<<<dim3(NBH, 16), 256, 0, stream>>>(bufW, bufA, bufD, bufC, bufG, bufE); // o -> E
  k_rms<<<dim3(LDIM, NBH), 64, 0, stream>>>(bufE, gn, bufC);                     // o_norm -> C

  k_f2bf<<<dim3(nDD/1024), 256, 0, stream>>>(Wo, bufB, nDD);
  k_gemm256<true><<<gg, 512, 0, stream>>>(bufC, bufB, d_out /*f32*/, TOK, DDIM, DDIM);
}